// Round 2
// baseline (897.432 us; speedup 1.0000x reference)
//
#include <hip/hip_runtime.h>
#include <hip/hip_bf16.h>
#include <stdint.h>

typedef __bf16  bf16x8  __attribute__((ext_vector_type(8)));
typedef float   floatx4 __attribute__((ext_vector_type(4)));

typedef __attribute__((address_space(1))) void gvoid_t;
typedef __attribute__((address_space(3))) void svoid_t;

// async global->LDS, 16B per lane; lds must be wave-uniform base (HW adds lane*16)
__device__ __forceinline__ void gld16(ushort* lds, const ushort* g) {
  __builtin_amdgcn_global_load_lds((gvoid_t*)g, (svoid_t*)lds, 16, 0, 0);
}

__device__ __forceinline__ ushort f2bf(float f) {
  union { float f; unsigned u; } v; v.f = f;
  unsigned u = v.u;
  return (ushort)((u + 0x7fffu + ((u >> 16) & 1u)) >> 16);  // RNE
}
__device__ __forceinline__ float bf2f(ushort h) {
  union { unsigned u; float f; } v; v.u = ((unsigned)h) << 16; return v.f;
}
// pack two fp32 -> bf16x2 dword (RNE, HW v_cvt_pk when available)
__device__ __forceinline__ unsigned pk2bf(float a, float b) {
  __hip_bfloat162 h = __float22bfloat162_rn(make_float2(a, b));
  union { __hip_bfloat162 h; unsigned u; } v; v.h = h; return v.u;
}

// ---------------------------------------------------------------- convert
__global__ __launch_bounds__(256) void cvt_f32_bf16(
    const float* __restrict__ in, ushort* __restrict__ out) {
  int i = blockIdx.x * 256 + threadIdx.x;
  float4 a = ((const float4*)in)[i];
  ushort4 o;
  o.x = f2bf(a.x); o.y = f2bf(a.y); o.z = f2bf(a.z); o.w = f2bf(a.w);
  ((ushort4*)out)[i] = o;
}

// ---------------------------------------------------------------- transpose
// out[C][R](bf16) = in[R][C](fp32)^T, 64x64 tiles
__global__ __launch_bounds__(256) void transpose_cvt(
    const float* __restrict__ in, ushort* __restrict__ out, int R, int C) {
  __shared__ ushort tile[64][65];
  const int r0 = blockIdx.y * 64, c0 = blockIdx.x * 64;
  const int t = threadIdx.x;
#pragma unroll
  for (int rep = 0; rep < 16; rep++) {
    int idx = rep * 256 + t;
    int r = idx >> 6, c = idx & 63;
    tile[r][c] = f2bf(in[(size_t)(r0 + r) * C + c0 + c]);
  }
  __syncthreads();
#pragma unroll
  for (int rep = 0; rep < 16; rep++) {
    int idx = rep * 256 + t;
    int r = idx >> 6, c = idx & 63;
    out[(size_t)(c0 + r) * R + r0 + c] = tile[c][r];
  }
}

// ---------------------------------------------------------------- GEMM 256x256
// C[M][N] = A[M][K] * Bt[N][K]^T. 256x256 tile, BK=64 (2 K-halves of 32),
// 8 waves (2Mx4N). LDS = 8 half-slots (2 dbuf x 2 khalf x {A,B}, 16KiB each).
// Schedule: 8 phases per 2 K-tiles; each phase stages ONE half-slot
// (2 gld16/wave) and computes one C-quadrant (16 MFMA). vmcnt(8) at odd-phase
// tails certifies each half-slot 4 phases after issue; never drains to 0.
// EPI 0: fp32 C store. EPI 1: scatter QKV (N=6144): Q,K -> [bh][s][128],
// V -> V^T [bh][128][s] (bf16).
template <int EPI>
__global__ __launch_bounds__(512, 2) void gemm256(
    const ushort* __restrict__ A, const ushort* __restrict__ Bt,
    float* __restrict__ Cf,
    ushort* __restrict__ C0, ushort* __restrict__ C1, ushort* __restrict__ C2,
    int M, int N, int K) {
  __shared__ __align__(16) ushort As[2][2][256 * 32];
  __shared__ __align__(16) ushort Bs[2][2][256 * 32];
  const int t = threadIdx.x;
  const int lane = t & 63;
  const int w = t >> 6;
  const int l15 = lane & 15;
  const int quad = lane >> 4;
  const int m0 = blockIdx.y * 256;
  const int n0 = blockIdx.x * 256;
  const int wmB = (w >> 2) * 128;  // wave's output-row base (2 M-groups)
  const int wnB = (w & 3) * 64;    // wave's output-col base (4 N-groups)

  // staging addressing: chunk ci = w*128 + j*64 + lane; row = ci>>2;
  // src chunk = (lane&3) ^ ((row>>1)&3)  (== (lane&3)^((lane>>3)&3))
  const int cS = (lane & 3) ^ ((lane >> 3) & 3);
  const size_t aoff = (size_t)(m0 + w * 32 + (lane >> 2)) * K + cS * 8;
  const size_t boff = (size_t)(n0 + w * 32 + (lane >> 2)) * K + cS * 8;

#define STAGE_A(db, kh, tile)                                                \
  { size_t ko_ = (size_t)(tile) * 64 + (kh) * 32;                            \
    gld16(&As[db][kh][w * 1024],       A + aoff + ko_);                      \
    gld16(&As[db][kh][w * 1024 + 512], A + aoff + 16 * (size_t)K + ko_); }
#define STAGE_B(db, kh, tile)                                                \
  { size_t ko_ = (size_t)(tile) * 64 + (kh) * 32;                            \
    gld16(&Bs[db][kh][w * 1024],       Bt + boff + ko_);                     \
    gld16(&Bs[db][kh][w * 1024 + 512], Bt + boff + 16 * (size_t)K + ko_); }

#define W8 asm volatile("s_waitcnt vmcnt(8)" ::: "memory");
#define W4 asm volatile("s_waitcnt vmcnt(4)" ::: "memory");
#define W0 asm volatile("s_waitcnt vmcnt(0)" ::: "memory");

  floatx4 acc[8][4];
  const floatx4 zero = {0.f, 0.f, 0.f, 0.f};
#pragma unroll
  for (int i = 0; i < 8; i++)
#pragma unroll
    for (int j = 0; j < 4; j++) acc[i][j] = zero;

  bf16x8 bfr[4];

  // phase: ds-read frags | stage one half-slot | bar | lgkm0 | 16 MFMA |
  //        [cert wait] | bar
#define PH(db, kh, mh, LB, STAGE, WAIT)                                        \
  {                                                                            \
    bf16x8 af[4];                                                              \
    {                                                                          \
      const ushort* Ah = &As[db][kh][0];                                       \
      _Pragma("unroll") for (int m_ = 0; m_ < 4; ++m_) {                       \
        int r_ = wmB + ((mh) * 4 + m_) * 16 + l15;                             \
        int c_ = quad ^ ((r_ >> 1) & 3);                                       \
        af[m_] = *(const bf16x8*)&Ah[r_ * 32 + c_ * 8];                        \
      }                                                                        \
      if (LB) {                                                                \
        const ushort* Bh = &Bs[db][kh][0];                                     \
        _Pragma("unroll") for (int n_ = 0; n_ < 4; ++n_) {                     \
          int r_ = wnB + n_ * 16 + l15;                                        \
          int c_ = quad ^ ((r_ >> 1) & 3);                                     \
          bfr[n_] = *(const bf16x8*)&Bh[r_ * 32 + c_ * 8];                     \
        }                                                                      \
      }                                                                        \
    }                                                                          \
    STAGE                                                                      \
    __builtin_amdgcn_s_barrier();                                              \
    asm volatile("s_waitcnt lgkmcnt(0)" ::: "memory");                         \
    __builtin_amdgcn_sched_barrier(0);                                         \
    __builtin_amdgcn_s_setprio(1);                                             \
    _Pragma("unroll") for (int m_ = 0; m_ < 4; ++m_)                           \
      _Pragma("unroll") for (int n_ = 0; n_ < 4; ++n_)                         \
        acc[(mh) * 4 + m_][n_] = __builtin_amdgcn_mfma_f32_16x16x32_bf16(      \
            af[m_], bfr[n_], acc[(mh) * 4 + m_][n_], 0, 0, 0);                 \
    __builtin_amdgcn_s_setprio(0);                                             \
    __builtin_amdgcn_sched_barrier(0);                                         \
    WAIT                                                                       \
    __builtin_amdgcn_s_barrier();                                              \
  }

  const int NI = K >> 7;  // iterations of 2 K-tiles

  // prologue: stage A(0,k0),B(0,k0),A(0,k1),B(0,k1),A(1,k0),B(1,k0);
  // certify first tile's k0 halves (drain oldest 4 of 12).
  STAGE_A(0, 0, 0);
  STAGE_B(0, 0, 0);
  STAGE_A(0, 1, 0);
  STAGE_B(0, 1, 0);
  STAGE_A(1, 0, 1);
  STAGE_B(1, 0, 1);
  W8
  __builtin_amdgcn_s_barrier();

  for (int i = 0; i < NI; ++i) {
    const int t1 = 2 * i + 1, t2 = 2 * i + 2, t3 = 2 * i + 3;
    if (i < NI - 1) {
      PH(0, 0, 0, 1, STAGE_A(1, 1, t1), )
      PH(0, 0, 1, 0, STAGE_B(1, 1, t1), W8)
      PH(0, 1, 0, 1, STAGE_A(0, 0, t2), )
      PH(0, 1, 1, 0, STAGE_B(0, 0, t2), W8)
      PH(1, 0, 0, 1, STAGE_A(0, 1, t2), )
      PH(1, 0, 1, 0, STAGE_B(0, 1, t2), W8)
      PH(1, 1, 0, 1, STAGE_A(1, 0, t3), )
      PH(1, 1, 1, 0, STAGE_B(1, 0, t3), W8)
    } else {
      // tail: no stages for tiles >= NT; waits tightened (ledger exact)
      PH(0, 0, 0, 1, STAGE_A(1, 1, t1), )
      PH(0, 0, 1, 0, STAGE_B(1, 1, t1), W8)
      PH(0, 1, 0, 1, , )
      PH(0, 1, 1, 0, , W4)
      PH(1, 0, 0, 1, , )
      PH(1, 0, 1, 0, , W0)
      PH(1, 1, 0, 1, , )
      PH(1, 1, 1, 0, , )
    }
  }

#undef PH
#undef STAGE_A
#undef STAGE_B
#undef W8
#undef W4
#undef W0

  if (EPI == 0) {
#pragma unroll
    for (int m = 0; m < 8; ++m)
#pragma unroll
      for (int n = 0; n < 4; ++n)
#pragma unroll
        for (int r = 0; r < 4; ++r) {
          int row = m0 + wmB + m * 16 + quad * 4 + r;
          int col = n0 + wnB + n * 16 + l15;
          Cf[(size_t)row * N + col] = acc[m][n][r];
        }
  } else {
    // wave's 64-col span lies within one head (and one of Q/K/V)
    const int colW = n0 + wnB;
    const int sel = colW >> 11;
    const int h = (colW >> 7) & 15;
    if (sel < 2) {
      ushort* dst = (sel == 0) ? C0 : C1;
#pragma unroll
      for (int m = 0; m < 8; ++m) {
        int rowb = m0 + wmB + m * 16 + quad * 4;
        int b = rowb >> 11, s = rowb & 2047;
#pragma unroll
        for (int n = 0; n < 4; ++n) {
          int d = (colW + n * 16 + l15) & 127;
#pragma unroll
          for (int r = 0; r < 4; ++r)
            dst[((size_t)(b * 16 + h) * 2048 + (s + r)) * 128 + d] =
                f2bf(acc[m][n][r]);
        }
      }
    } else {
#pragma unroll
      for (int m = 0; m < 8; ++m) {
        int rowb = m0 + wmB + m * 16 + quad * 4;
        int b = rowb >> 11, s = rowb & 2047;
#pragma unroll
        for (int n = 0; n < 4; ++n) {
          int d = (colW + n * 16 + l15) & 127;
          ushort4 pk;
          pk.x = f2bf(acc[m][n][0]);
          pk.y = f2bf(acc[m][n][1]);
          pk.z = f2bf(acc[m][n][2]);
          pk.w = f2bf(acc[m][n][3]);
          *(ushort4*)&C2[((size_t)(b * 16 + h) * 128 + d) * 2048 + s] = pk;
        }
      }
    }
  }
}

// ---------------------------------------------------------------- RoPE
// in-place on Q and K planes: [bh][s][128]. Q additionally pre-scaled by
// (1/sqrt(128))*log2(e) so attention can use exp2 with no per-tile scaling.
__global__ __launch_bounds__(256) void rope_kernel(
    ushort* __restrict__ Q, ushort* __restrict__ Kb,
    const float* __restrict__ cosT, const float* __restrict__ sinT) {
  unsigned gid = blockIdx.x * 256u + threadIdx.x;
  int d = gid & 63;
  int s = (gid >> 6) & 2047;
  int bh = (gid >> 17) & 63;
  const bool isK = (gid >> 23) != 0;
  ushort* buf = isK ? Kb : Q;
  const float sc = isK ? 1.0f
                       : 0.08838834764831845f * 1.4426950408889634f;
  size_t base = ((size_t)bh * 2048 + s) * 128;
  float x1 = bf2f(buf[base + d]);
  float x2 = bf2f(buf[base + d + 64]);
  float c = cosT[s * 64 + d];
  float sn = sinT[s * 64 + d];
  buf[base + d] = f2bf((x1 * c - x2 * sn) * sc);
  buf[base + d + 64] = f2bf((x1 * sn + x2 * c) * sc);
}

// ---------------------------------------------------------------- attention
// flash-style causal attention, transposed-score form.
// Grid: 1-D, 2048 blocks, heavy-first: tq = 31-(bid>>6), bh = bid&63.
// Q-tile = 64 rows, 4 waves x 16 q. Per wave: S^T = K.Q^T (q = lane&15),
// per-lane scalar online softmax, P^T -> LDS (b64), O^T = V^T.P^T.
// Q [bh][s][128] (pre-scaled), K [bh][s][128], VT [bh][128][s],
// O -> [b][s][h*128+d] (bf16)
__global__ __launch_bounds__(256, 4) void attn_kernel(
    const ushort* __restrict__ Q, const ushort* __restrict__ Kb,
    const ushort* __restrict__ VT, ushort* __restrict__ O) {
  __shared__ __align__(16) ushort Ks[64 * 128];  // [k_local][d], xor(row&15)
  __shared__ __align__(16) ushort Vs[128 * 64];  // [d][s_local], xor(row&7)
  __shared__ __align__(16) ushort Ps[64 * 64];   // [q_local][k], 8-el grp xor(l15&7)
  const int t = threadIdx.x, lane = t & 63, w = t >> 6;
  const int l15 = lane & 15, quad = lane >> 4;
  const int bid = blockIdx.x;
  const int tq = 31 - (bid >> 6);   // heavy-first
  const int bh = bid & 63;
  const int q0 = tq * 64 + w * 16;
  const int qrow = q0 + l15;        // this lane's q row
  const size_t hbase = (size_t)bh * 2048 * 128;
  const float NEGINF = -__builtin_inff();

  // Q fragments (B-operand): n=q=l15, k=d contiguous 8
  bf16x8 aq[4];
#pragma unroll
  for (int kb = 0; kb < 4; kb++)
    aq[kb] = *(const bf16x8*)&Q[hbase + (size_t)qrow * 128 + kb * 32 + quad * 8];

  float m2 = NEGINF, lsum = 0.f;
  floatx4 oacc[8];  // O^T: row d = dj*16+quad*4+r, col q = l15
  const floatx4 zero = {0.f, 0.f, 0.f, 0.f};
#pragma unroll
  for (int dj = 0; dj < 8; dj++) oacc[dj] = zero;

  const int ntk = tq + 1;

  for (int tk = 0; tk < ntk; tk++) {
    __syncthreads();
#pragma unroll
    for (int it = 0; it < 4; it++) {
      int o = (w * 4 + it) * 64 + lane;
      {  // K tile: 64 rows x 128 el
        int row = o >> 4;
        int c = (o & 15) ^ (row & 15);
        gld16(&Ks[(w * 4 + it) * 512],
              Kb + hbase + (size_t)(tk * 64 + row) * 128 + c * 8);
      }
      {  // V^T tile: 128 rows x 64 el
        int row = o >> 3;
        int c = (o & 7) ^ (row & 7);
        gld16(&Vs[(w * 4 + it) * 512],
              VT + hbase + (size_t)row * 2048 + tk * 64 + c * 8);
      }
    }
    __syncthreads();

    // ---- S^T = K.Q^T : sacc[j] rows k = j*16+quad*4+r, col q = l15
    floatx4 sacc[4];
#pragma unroll
    for (int j = 0; j < 4; j++) sacc[j] = zero;
#pragma unroll
    for (int kb = 0; kb < 4; kb++) {
#pragma unroll
      for (int j = 0; j < 4; j++) {
        int row = j * 16 + l15;
        int c = (kb * 4 + quad) ^ (row & 15);
        bf16x8 kf = *(const bf16x8*)&Ks[row * 128 + c * 8];
        sacc[j] = __builtin_amdgcn_mfma_f32_16x16x32_bf16(kf, aq[kb], sacc[j],
                                                          0, 0, 0);
      }
    }

    // ---- causal mask (diagonal tile only); scores already in log2 domain
    if (tk == tq) {
#pragma unroll
      for (int j = 0; j < 4; j++)
#pragma unroll
        for (int r = 0; r < 4; r++) {
          int kcol = tk * 64 + j * 16 + quad * 4 + r;
          if (kcol > qrow) sacc[j][r] = NEGINF;
        }
    }

    // ---- per-lane scalar online softmax (row q = l15)
    float mx = sacc[0][0];
#pragma unroll
    for (int j = 0; j < 4; j++)
#pragma unroll
      for (int r = 0; r < 4; r++) mx = fmaxf(mx, sacc[j][r]);
    mx = fmaxf(mx, __shfl_xor(mx, 16));
    mx = fmaxf(mx, __shfl_xor(mx, 32));
    float mnew = fmaxf(m2, mx);
    float alpha = __builtin_exp2f(m2 - mnew);
    m2 = mnew;
    float rs = 0.f;
#pragma unroll
    for (int j = 0; j < 4; j++)
#pragma unroll
      for (int r = 0; r < 4; r++) {
        float p = __builtin_exp2f(sacc[j][r] - mnew);
        sacc[j][r] = p;
        rs += p;
      }
    rs += __shfl_xor(rs, 16);
    rs += __shfl_xor(rs, 32);
    lsum = lsum * alpha + rs;
    if (__any(alpha < 1.0f)) {
#pragma unroll
      for (int dj = 0; dj < 8; dj++) oacc[dj] *= alpha;
    }

    // ---- P^T -> LDS: row q_local = w*16+l15, 4 consecutive k per write.
    // 8-element groups swizzled: g' = g ^ (l15&7)
#pragma unroll
    for (int j = 0; j < 4; j++) {
      unsigned lo = pk2bf(sacc[j][0], sacc[j][1]);
      unsigned hi = pk2bf(sacc[j][2], sacc[j][3]);
      int g = j * 2 + (quad >> 1);
      int gp = g ^ (l15 & 7);
      uint2 pv; pv.x = lo; pv.y = hi;
      *(uint2*)&Ps[(w * 16 + l15) * 64 + gp * 8 + (quad & 1) * 4] = pv;
    }

    // ---- O^T += V^T . P^T  (same-wave Ps write->read, per-wave rows)
    bf16x8 bp[2];
#pragma unroll
    for (int kk = 0; kk < 2; kk++) {
      int g = kk * 4 + quad;
      int gp = g ^ (l15 & 7);
      bp[kk] = *(const bf16x8*)&Ps[(w * 16 + l15) * 64 + gp * 8];
    }
#pragma unroll
    for (int kk = 0; kk < 2; kk++)
#pragma unroll
      for (int dj = 0; dj < 8; dj++) {
        int rowd = dj * 16 + l15;
        int c = (kk * 4 + quad) ^ (rowd & 7);
        bf16x8 av = *(const bf16x8*)&Vs[rowd * 64 + c * 8];
        oacc[dj] = __builtin_amdgcn_mfma_f32_16x16x32_bf16(av, bp[kk], oacc[dj],
                                                           0, 0, 0);
      }
  }

  // epilogue: O^T lane holds col q = l15, rows d = dj*16+quad*4+r
  const int b = bh >> 4, h = bh & 15;
  const float rl = 1.0f / lsum;
  const size_t obase = ((size_t)(b * 2048 + qrow)) * 2048 + h * 128;
#pragma unroll
  for (int dj = 0; dj < 8; dj++) {
    ushort4 pk;
    pk.x = f2bf(oacc[dj][0] * rl);
    pk.y = f2bf(oacc[dj][1] * rl);
    pk.z = f2bf(oacc[dj][2] * rl);
    pk.w = f2bf(oacc[dj][3] * rl);
    *(ushort4*)&O[obase + dj * 16 + quad * 4] = pk;
  }
}

// ---------------------------------------------------------------- launch
// All inputs/outputs fp32 (per reference). bf16 scratch:
//   d_out[0 .. 33.5MB)  : xbf (bf16 x), dead before GEMM2 overwrites d_out
//   ws[0, 33.5M)        : wqkvT (GEMM1 only) then Ob (attn -> GEMM2)
//   ws[33.5M, 42.0M)    : woutT
//   ws[42.0M, 75.5M)    : Q   [64][2048][128]
//   ws[75.5M, 109.1M)   : K   [64][2048][128]
//   ws[109.1M, 142.6M)  : VT  [64][128][2048]
extern "C" void kernel_launch(void* const* d_in, const int* in_sizes, int n_in,
                              void* d_out, int out_size, void* d_ws, size_t ws_size,
                              hipStream_t stream) {
  const float* x    = (const float*)d_in[0];
  const float* cosT = (const float*)d_in[1];
  const float* sinT = (const float*)d_in[2];
  const float* wqkv = (const float*)d_in[3];
  const float* wout = (const float*)d_in[4];
  float* out = (float*)d_out;
  char* ws = (char*)d_ws;

  ushort* xbf   = (ushort*)d_out;                      // 8192x2048 bf16 scratch
  ushort* wqkvT = (ushort*)(ws);                       // 6144x2048
  ushort* Ob    = (ushort*)(ws);                       // 8192x2048 (after GEMM1)
  ushort* woutT = (ushort*)(ws + 33554432);            // 2048x2048
  ushort* Qb    = (ushort*)(ws + 41943040);
  ushort* Kbuf  = (ushort*)(ws + 75497472);
  ushort* VTb   = (ushort*)(ws + 109051904);

  cvt_f32_bf16<<<16384, 256, 0, stream>>>(x, xbf);
  transpose_cvt<<<dim3(96, 32), 256, 0, stream>>>(wqkv, wqkvT, 2048, 6144);
  transpose_cvt<<<dim3(32, 32), 256, 0, stream>>>(wout, woutT, 2048, 2048);
  gemm256<1><<<dim3(24, 32), 512, 0, stream>>>(xbf, wqkvT, nullptr,
                                               Qb, Kbuf, VTb, 8192, 6144, 2048);
  rope_kernel<<<65536, 256, 0, stream>>>(Qb, Kbuf, cosT, sinT);
  attn_kernel<<<2048, 256, 0, stream>>>(Qb, Kbuf, VTb, Ob);
  gemm256<0><<<dim3(8, 32), 512, 0, stream>>>(Ob, woutT, out,
                                              nullptr, nullptr, nullptr,
                                              8192, 2048, 2048);
}

// Round 3
// 894.262 us; speedup vs baseline: 1.0035x; 1.0035x over previous
//
#include <hip/hip_runtime.h>
#include <hip/hip_bf16.h>
#include <stdint.h>

typedef __bf16  bf16x8  __attribute__((ext_vector_type(8)));
typedef float   floatx4 __attribute__((ext_vector_type(4)));

typedef __attribute__((address_space(1))) void gvoid_t;
typedef __attribute__((address_space(3))) void svoid_t;

// async global->LDS, 16B per lane; lds must be wave-uniform base (HW adds lane*16)
__device__ __forceinline__ void gld16(ushort* lds, const ushort* g) {
  __builtin_amdgcn_global_load_lds((gvoid_t*)g, (svoid_t*)lds, 16, 0, 0);
}

__device__ __forceinline__ ushort f2bf(float f) {
  union { float f; unsigned u; } v; v.f = f;
  unsigned u = v.u;
  return (ushort)((u + 0x7fffu + ((u >> 16) & 1u)) >> 16);  // RNE
}
__device__ __forceinline__ float bf2f(ushort h) {
  union { unsigned u; float f; } v; v.u = ((unsigned)h) << 16; return v.f;
}
// pack two fp32 -> bf16x2 dword (RNE, HW v_cvt_pk when available)
__device__ __forceinline__ unsigned pk2bf(float a, float b) {
  __hip_bfloat162 h = __float22bfloat162_rn(make_float2(a, b));
  union { __hip_bfloat162 h; unsigned u; } v; v.h = h; return v.u;
}

// ---------------------------------------------------------------- convert
__global__ __launch_bounds__(256) void cvt_f32_bf16(
    const float* __restrict__ in, ushort* __restrict__ out) {
  int i = blockIdx.x * 256 + threadIdx.x;
  float4 a = ((const float4*)in)[i];
  ushort4 o;
  o.x = f2bf(a.x); o.y = f2bf(a.y); o.z = f2bf(a.z); o.w = f2bf(a.w);
  ((ushort4*)out)[i] = o;
}

// ---------------------------------------------------------------- transpose
// out[C][R](bf16) = in[R][C](fp32)^T, 64x64 tiles
__global__ __launch_bounds__(256) void transpose_cvt(
    const float* __restrict__ in, ushort* __restrict__ out, int R, int C) {
  __shared__ ushort tile[64][65];
  const int r0 = blockIdx.y * 64, c0 = blockIdx.x * 64;
  const int t = threadIdx.x;
#pragma unroll
  for (int rep = 0; rep < 16; rep++) {
    int idx = rep * 256 + t;
    int r = idx >> 6, c = idx & 63;
    tile[r][c] = f2bf(in[(size_t)(r0 + r) * C + c0 + c]);
  }
  __syncthreads();
#pragma unroll
  for (int rep = 0; rep < 16; rep++) {
    int idx = rep * 256 + t;
    int r = idx >> 6, c = idx & 63;
    out[(size_t)(c0 + r) * R + r0 + c] = tile[c][r];
  }
}

// ---------------------------------------------------------------- GEMM 256x256
// C[M][N] = A[M][K] * Bt[N][K]^T. 256x256 tile, BK=64 (2 K-halves of 32),
// 8 waves (2Mx4N). LDS = 8 half-slots (2 dbuf x 2 khalf x {A,B}, 16KiB each).
// Schedule: 8 phases per 2 K-tiles; each phase stages ONE half-slot
// (2 gld16/wave) and computes one C-quadrant (16 MFMA). vmcnt(8) at odd-phase
// tails certifies each half-slot 4 phases after issue; never drains to 0.
// __launch_bounds__(512, 1): LDS (128KiB) already caps at 1 block/CU; asking
// for 2 waves/SIMD caps the unified VGPR+AGPR file at 256/wave and spills the
// 128-reg accumulator (round-2 post-mortem: +640MB WRITE_SIZE). min-waves=1
// gives the 512-reg budget; occupancy is unchanged (LDS-capped).
// EPI 0: fp32 C store. EPI 1: scatter QKV (N=6144): Q,K -> [bh][s][128],
// V -> V^T [bh][128][s] (bf16).
template <int EPI>
__global__ __launch_bounds__(512, 1) void gemm256(
    const ushort* __restrict__ A, const ushort* __restrict__ Bt,
    float* __restrict__ Cf,
    ushort* __restrict__ C0, ushort* __restrict__ C1, ushort* __restrict__ C2,
    int M, int N, int K) {
  __shared__ __align__(16) ushort As[2][2][256 * 32];
  __shared__ __align__(16) ushort Bs[2][2][256 * 32];
  const int t = threadIdx.x;
  const int lane = t & 63;
  const int w = t >> 6;
  const int l15 = lane & 15;
  const int quad = lane >> 4;
  const int m0 = blockIdx.y * 256;
  const int n0 = blockIdx.x * 256;
  const int wmB = (w >> 2) * 128;  // wave's output-row base (2 M-groups)
  const int wnB = (w & 3) * 64;    // wave's output-col base (4 N-groups)

  // staging addressing: chunk ci = w*128 + j*64 + lane; row = ci>>2;
  // src chunk = (lane&3) ^ ((row>>1)&3)  (== (lane&3)^((lane>>3)&3))
  const int cS = (lane & 3) ^ ((lane >> 3) & 3);
  const size_t aoff = (size_t)(m0 + w * 32 + (lane >> 2)) * K + cS * 8;
  const size_t boff = (size_t)(n0 + w * 32 + (lane >> 2)) * K + cS * 8;

#define STAGE_A(db, kh, tile)                                                \
  { size_t ko_ = (size_t)(tile) * 64 + (kh) * 32;                            \
    gld16(&As[db][kh][w * 1024],       A + aoff + ko_);                      \
    gld16(&As[db][kh][w * 1024 + 512], A + aoff + 16 * (size_t)K + ko_); }
#define STAGE_B(db, kh, tile)                                                \
  { size_t ko_ = (size_t)(tile) * 64 + (kh) * 32;                            \
    gld16(&Bs[db][kh][w * 1024],       Bt + boff + ko_);                     \
    gld16(&Bs[db][kh][w * 1024 + 512], Bt + boff + 16 * (size_t)K + ko_); }

#define W8 asm volatile("s_waitcnt vmcnt(8)" ::: "memory");
#define W4 asm volatile("s_waitcnt vmcnt(4)" ::: "memory");
#define W0 asm volatile("s_waitcnt vmcnt(0)" ::: "memory");

  floatx4 acc[8][4];
  const floatx4 zero = {0.f, 0.f, 0.f, 0.f};
#pragma unroll
  for (int i = 0; i < 8; i++)
#pragma unroll
    for (int j = 0; j < 4; j++) acc[i][j] = zero;

  bf16x8 bfr[4];

  // phase: ds-read frags | stage one half-slot | bar | lgkm0 | 16 MFMA |
  //        [cert wait] | bar
#define PH(db, kh, mh, LB, STAGE, WAIT)                                        \
  {                                                                            \
    bf16x8 af[4];                                                              \
    {                                                                          \
      const ushort* Ah = &As[db][kh][0];                                       \
      _Pragma("unroll") for (int m_ = 0; m_ < 4; ++m_) {                       \
        int r_ = wmB + ((mh) * 4 + m_) * 16 + l15;                             \
        int c_ = quad ^ ((r_ >> 1) & 3);                                       \
        af[m_] = *(const bf16x8*)&Ah[r_ * 32 + c_ * 8];                        \
      }                                                                        \
      if (LB) {                                                                \
        const ushort* Bh = &Bs[db][kh][0];                                     \
        _Pragma("unroll") for (int n_ = 0; n_ < 4; ++n_) {                     \
          int r_ = wnB + n_ * 16 + l15;                                        \
          int c_ = quad ^ ((r_ >> 1) & 3);                                     \
          bfr[n_] = *(const bf16x8*)&Bh[r_ * 32 + c_ * 8];                     \
        }                                                                      \
      }                                                                        \
    }                                                                          \
    STAGE                                                                      \
    __builtin_amdgcn_s_barrier();                                              \
    asm volatile("s_waitcnt lgkmcnt(0)" ::: "memory");                         \
    __builtin_amdgcn_sched_barrier(0);                                         \
    __builtin_amdgcn_s_setprio(1);                                             \
    _Pragma("unroll") for (int m_ = 0; m_ < 4; ++m_)                           \
      _Pragma("unroll") for (int n_ = 0; n_ < 4; ++n_)                         \
        acc[(mh) * 4 + m_][n_] = __builtin_amdgcn_mfma_f32_16x16x32_bf16(      \
            af[m_], bfr[n_], acc[(mh) * 4 + m_][n_], 0, 0, 0);                 \
    __builtin_amdgcn_s_setprio(0);                                             \
    __builtin_amdgcn_sched_barrier(0);                                         \
    WAIT                                                                       \
    __builtin_amdgcn_s_barrier();                                              \
  }

  const int NI = K >> 7;  // iterations of 2 K-tiles

  // prologue: stage A(0,k0),B(0,k0),A(0,k1),B(0,k1),A(1,k0),B(1,k0);
  // certify first tile's k0 halves (drain oldest 4 of 12).
  STAGE_A(0, 0, 0);
  STAGE_B(0, 0, 0);
  STAGE_A(0, 1, 0);
  STAGE_B(0, 1, 0);
  STAGE_A(1, 0, 1);
  STAGE_B(1, 0, 1);
  W8
  __builtin_amdgcn_s_barrier();

  for (int i = 0; i < NI; ++i) {
    const int t1 = 2 * i + 1, t2 = 2 * i + 2, t3 = 2 * i + 3;
    if (i < NI - 1) {
      PH(0, 0, 0, 1, STAGE_A(1, 1, t1), )
      PH(0, 0, 1, 0, STAGE_B(1, 1, t1), W8)
      PH(0, 1, 0, 1, STAGE_A(0, 0, t2), )
      PH(0, 1, 1, 0, STAGE_B(0, 0, t2), W8)
      PH(1, 0, 0, 1, STAGE_A(0, 1, t2), )
      PH(1, 0, 1, 0, STAGE_B(0, 1, t2), W8)
      PH(1, 1, 0, 1, STAGE_A(1, 0, t3), )
      PH(1, 1, 1, 0, STAGE_B(1, 0, t3), W8)
    } else {
      // tail: no stages for tiles >= NT; waits tightened (ledger exact)
      PH(0, 0, 0, 1, STAGE_A(1, 1, t1), )
      PH(0, 0, 1, 0, STAGE_B(1, 1, t1), W8)
      PH(0, 1, 0, 1, , )
      PH(0, 1, 1, 0, , W4)
      PH(1, 0, 0, 1, , )
      PH(1, 0, 1, 0, , W0)
      PH(1, 1, 0, 1, , )
      PH(1, 1, 1, 0, , )
    }
  }

#undef PH
#undef STAGE_A
#undef STAGE_B
#undef W8
#undef W4
#undef W0

  if (EPI == 0) {
#pragma unroll
    for (int m = 0; m < 8; ++m)
#pragma unroll
      for (int n = 0; n < 4; ++n)
#pragma unroll
        for (int r = 0; r < 4; ++r) {
          int row = m0 + wmB + m * 16 + quad * 4 + r;
          int col = n0 + wnB + n * 16 + l15;
          Cf[(size_t)row * N + col] = acc[m][n][r];
        }
  } else {
    // wave's 64-col span lies within one head (and one of Q/K/V)
    const int colW = n0 + wnB;
    const int sel = colW >> 11;
    const int h = (colW >> 7) & 15;
    if (sel < 2) {
      ushort* dst = (sel == 0) ? C0 : C1;
#pragma unroll
      for (int m = 0; m < 8; ++m) {
        int rowb = m0 + wmB + m * 16 + quad * 4;
        int b = rowb >> 11, s = rowb & 2047;
#pragma unroll
        for (int n = 0; n < 4; ++n) {
          int d = (colW + n * 16 + l15) & 127;
#pragma unroll
          for (int r = 0; r < 4; ++r)
            dst[((size_t)(b * 16 + h) * 2048 + (s + r)) * 128 + d] =
                f2bf(acc[m][n][r]);
        }
      }
    } else {
#pragma unroll
      for (int m = 0; m < 8; ++m) {
        int rowb = m0 + wmB + m * 16 + quad * 4;
        int b = rowb >> 11, s = rowb & 2047;
#pragma unroll
        for (int n = 0; n < 4; ++n) {
          int d = (colW + n * 16 + l15) & 127;
          ushort4 pk;
          pk.x = f2bf(acc[m][n][0]);
          pk.y = f2bf(acc[m][n][1]);
          pk.z = f2bf(acc[m][n][2]);
          pk.w = f2bf(acc[m][n][3]);
          *(ushort4*)&C2[((size_t)(b * 16 + h) * 128 + d) * 2048 + s] = pk;
        }
      }
    }
  }
}

// ---------------------------------------------------------------- RoPE
// in-place on Q and K planes: [bh][s][128]. Q additionally pre-scaled by
// (1/sqrt(128))*log2(e) so attention can use exp2 with no per-tile scaling.
__global__ __launch_bounds__(256) void rope_kernel(
    ushort* __restrict__ Q, ushort* __restrict__ Kb,
    const float* __restrict__ cosT, const float* __restrict__ sinT) {
  unsigned gid = blockIdx.x * 256u + threadIdx.x;
  int d = gid & 63;
  int s = (gid >> 6) & 2047;
  int bh = (gid >> 17) & 63;
  const bool isK = (gid >> 23) != 0;
  ushort* buf = isK ? Kb : Q;
  const float sc = isK ? 1.0f
                       : 0.08838834764831845f * 1.4426950408889634f;
  size_t base = ((size_t)bh * 2048 + s) * 128;
  float x1 = bf2f(buf[base + d]);
  float x2 = bf2f(buf[base + d + 64]);
  float c = cosT[s * 64 + d];
  float sn = sinT[s * 64 + d];
  buf[base + d] = f2bf((x1 * c - x2 * sn) * sc);
  buf[base + d + 64] = f2bf((x1 * sn + x2 * c) * sc);
}

// ---------------------------------------------------------------- attention
// flash-style causal attention, transposed-score form.
// Grid: 1-D, 2048 blocks, heavy-first: tq = 31-(bid>>6), bh = bid&63.
// Q-tile = 64 rows, 4 waves x 16 q. Per wave: S^T = K.Q^T (q = lane&15),
// per-lane scalar online softmax, P^T -> LDS (b64), O^T = V^T.P^T.
// Q [bh][s][128] (pre-scaled), K [bh][s][128], VT [bh][128][s],
// O -> [b][s][h*128+d] (bf16)
__global__ __launch_bounds__(256, 4) void attn_kernel(
    const ushort* __restrict__ Q, const ushort* __restrict__ Kb,
    const ushort* __restrict__ VT, ushort* __restrict__ O) {
  __shared__ __align__(16) ushort Ks[64 * 128];  // [k_local][d], xor(row&15)
  __shared__ __align__(16) ushort Vs[128 * 64];  // [d][s_local], xor(row&7)
  __shared__ __align__(16) ushort Ps[64 * 64];   // [q_local][k], 8-el grp xor(l15&7)
  const int t = threadIdx.x, lane = t & 63, w = t >> 6;
  const int l15 = lane & 15, quad = lane >> 4;
  const int bid = blockIdx.x;
  const int tq = 31 - (bid >> 6);   // heavy-first
  const int bh = bid & 63;
  const int q0 = tq * 64 + w * 16;
  const int qrow = q0 + l15;        // this lane's q row
  const size_t hbase = (size_t)bh * 2048 * 128;
  const float NEGINF = -__builtin_inff();

  // Q fragments (B-operand): n=q=l15, k=d contiguous 8
  bf16x8 aq[4];
#pragma unroll
  for (int kb = 0; kb < 4; kb++)
    aq[kb] = *(const bf16x8*)&Q[hbase + (size_t)qrow * 128 + kb * 32 + quad * 8];

  float m2 = NEGINF, lsum = 0.f;
  floatx4 oacc[8];  // O^T: row d = dj*16+quad*4+r, col q = l15
  const floatx4 zero = {0.f, 0.f, 0.f, 0.f};
#pragma unroll
  for (int dj = 0; dj < 8; dj++) oacc[dj] = zero;

  const int ntk = tq + 1;

  for (int tk = 0; tk < ntk; tk++) {
    __syncthreads();
#pragma unroll
    for (int it = 0; it < 4; it++) {
      int o = (w * 4 + it) * 64 + lane;
      {  // K tile: 64 rows x 128 el
        int row = o >> 4;
        int c = (o & 15) ^ (row & 15);
        gld16(&Ks[(w * 4 + it) * 512],
              Kb + hbase + (size_t)(tk * 64 + row) * 128 + c * 8);
      }
      {  // V^T tile: 128 rows x 64 el
        int row = o >> 3;
        int c = (o & 7) ^ (row & 7);
        gld16(&Vs[(w * 4 + it) * 512],
              VT + hbase + (size_t)row * 2048 + tk * 64 + c * 8);
      }
    }
    __syncthreads();

    // ---- S^T = K.Q^T : sacc[j] rows k = j*16+quad*4+r, col q = l15
    floatx4 sacc[4];
#pragma unroll
    for (int j = 0; j < 4; j++) sacc[j] = zero;
#pragma unroll
    for (int kb = 0; kb < 4; kb++) {
#pragma unroll
      for (int j = 0; j < 4; j++) {
        int row = j * 16 + l15;
        int c = (kb * 4 + quad) ^ (row & 15);
        bf16x8 kf = *(const bf16x8*)&Ks[row * 128 + c * 8];
        sacc[j] = __builtin_amdgcn_mfma_f32_16x16x32_bf16(kf, aq[kb], sacc[j],
                                                          0, 0, 0);
      }
    }

    // ---- causal mask (diagonal tile only); scores already in log2 domain
    if (tk == tq) {
#pragma unroll
      for (int j = 0; j < 4; j++)
#pragma unroll
        for (int r = 0; r < 4; r++) {
          int kcol = tk * 64 + j * 16 + quad * 4 + r;
          if (kcol > qrow) sacc[j][r] = NEGINF;
        }
    }

    // ---- per-lane scalar online softmax (row q = l15)
    float mx = sacc[0][0];
#pragma unroll
    for (int j = 0; j < 4; j++)
#pragma unroll
      for (int r = 0; r < 4; r++) mx = fmaxf(mx, sacc[j][r]);
    mx = fmaxf(mx, __shfl_xor(mx, 16));
    mx = fmaxf(mx, __shfl_xor(mx, 32));
    float mnew = fmaxf(m2, mx);
    float alpha = __builtin_exp2f(m2 - mnew);
    m2 = mnew;
    float rs = 0.f;
#pragma unroll
    for (int j = 0; j < 4; j++)
#pragma unroll
      for (int r = 0; r < 4; r++) {
        float p = __builtin_exp2f(sacc[j][r] - mnew);
        sacc[j][r] = p;
        rs += p;
      }
    rs += __shfl_xor(rs, 16);
    rs += __shfl_xor(rs, 32);
    lsum = lsum * alpha + rs;
    if (__any(alpha < 1.0f)) {
#pragma unroll
      for (int dj = 0; dj < 8; dj++) oacc[dj] *= alpha;
    }

    // ---- P^T -> LDS: row q_local = w*16+l15, 4 consecutive k per write.
    // 8-element groups swizzled: g' = g ^ (l15&7)
#pragma unroll
    for (int j = 0; j < 4; j++) {
      unsigned lo = pk2bf(sacc[j][0], sacc[j][1]);
      unsigned hi = pk2bf(sacc[j][2], sacc[j][3]);
      int g = j * 2 + (quad >> 1);
      int gp = g ^ (l15 & 7);
      uint2 pv; pv.x = lo; pv.y = hi;
      *(uint2*)&Ps[(w * 16 + l15) * 64 + gp * 8 + (quad & 1) * 4] = pv;
    }

    // ---- O^T += V^T . P^T  (same-wave Ps write->read, per-wave rows)
    bf16x8 bp[2];
#pragma unroll
    for (int kk = 0; kk < 2; kk++) {
      int g = kk * 4 + quad;
      int gp = g ^ (l15 & 7);
      bp[kk] = *(const bf16x8*)&Ps[(w * 16 + l15) * 64 + gp * 8];
    }
#pragma unroll
    for (int kk = 0; kk < 2; kk++)
#pragma unroll
      for (int dj = 0; dj < 8; dj++) {
        int rowd = dj * 16 + l15;
        int c = (kk * 4 + quad) ^ (rowd & 7);
        bf16x8 av = *(const bf16x8*)&Vs[rowd * 64 + c * 8];
        oacc[dj] = __builtin_amdgcn_mfma_f32_16x16x32_bf16(av, bp[kk], oacc[dj],
                                                           0, 0, 0);
      }
  }

  // epilogue: O^T lane holds col q = l15, rows d = dj*16+quad*4+r
  const int b = bh >> 4, h = bh & 15;
  const float rl = 1.0f / lsum;
  const size_t obase = ((size_t)(b * 2048 + qrow)) * 2048 + h * 128;
#pragma unroll
  for (int dj = 0; dj < 8; dj++) {
    ushort4 pk;
    pk.x = f2bf(oacc[dj][0] * rl);
    pk.y = f2bf(oacc[dj][1] * rl);
    pk.z = f2bf(oacc[dj][2] * rl);
    pk.w = f2bf(oacc[dj][3] * rl);
    *(ushort4*)&O[obase + dj * 16 + quad * 4] = pk;
  }
}

// ---------------------------------------------------------------- launch
// All inputs/outputs fp32 (per reference). bf16 scratch:
//   d_out[0 .. 33.5MB)  : xbf (bf16 x), dead before GEMM2 overwrites d_out
//   ws[0, 33.5M)        : wqkvT (GEMM1 only) then Ob (attn -> GEMM2)
//   ws[33.5M, 42.0M)    : woutT
//   ws[42.0M, 75.5M)    : Q   [64][2048][128]
//   ws[75.5M, 109.1M)   : K   [64][2048][128]
//   ws[109.1M, 142.6M)  : VT  [64][128][2048]
extern "C" void kernel_launch(void* const* d_in, const int* in_sizes, int n_in,
                              void* d_out, int out_size, void* d_ws, size_t ws_size,
                              hipStream_t stream) {
  const float* x    = (const float*)d_in[0];
  const float* cosT = (const float*)d_in[1];
  const float* sinT = (const float*)d_in[2];
  const float* wqkv = (const float*)d_in[3];
  const float* wout = (const float*)d_in[4];
  float* out = (float*)d_out;
  char* ws = (char*)d_ws;

  ushort* xbf   = (ushort*)d_out;                      // 8192x2048 bf16 scratch
  ushort* wqkvT = (ushort*)(ws);                       // 6144x2048
  ushort* Ob    = (ushort*)(ws);                       // 8192x2048 (after GEMM1)
  ushort* woutT = (ushort*)(ws + 33554432);            // 2048x2048
  ushort* Qb    = (ushort*)(ws + 41943040);
  ushort* Kbuf  = (ushort*)(ws + 75497472);
  ushort* VTb   = (ushort*)(ws + 109051904);

  cvt_f32_bf16<<<16384, 256, 0, stream>>>(x, xbf);
  transpose_cvt<<<dim3(96, 32), 256, 0, stream>>>(wqkv, wqkvT, 2048, 6144);
  transpose_cvt<<<dim3(32, 32), 256, 0, stream>>>(wout, woutT, 2048, 2048);
  gemm256<1><<<dim3(24, 32), 512, 0, stream>>>(xbf, wqkvT, nullptr,
                                               Qb, Kbuf, VTb, 8192, 6144, 2048);
  rope_kernel<<<65536, 256, 0, stream>>>(Qb, Kbuf, cosT, sinT);
  attn_kernel<<<2048, 256, 0, stream>>>(Qb, Kbuf, VTb, Ob);
  gemm256<0><<<dim3(8, 32), 512, 0, stream>>>(Ob, woutT, out,
                                              nullptr, nullptr, nullptr,
                                              8192, 2048, 2048);
}

// Round 4
// 620.485 us; speedup vs baseline: 1.4463x; 1.4412x over previous
//
#include <hip/hip_runtime.h>
#include <hip/hip_bf16.h>
#include <stdint.h>

typedef __bf16  bf16x8  __attribute__((ext_vector_type(8)));
typedef float   floatx4 __attribute__((ext_vector_type(4)));

typedef __attribute__((address_space(1))) void gvoid_t;
typedef __attribute__((address_space(3))) void svoid_t;

// async global->LDS, 16B per lane; lds must be wave-uniform base (HW adds lane*16)
__device__ __forceinline__ void gld16(ushort* lds, const ushort* g) {
  __builtin_amdgcn_global_load_lds((gvoid_t*)g, (svoid_t*)lds, 16, 0, 0);
}

__device__ __forceinline__ ushort f2bf(float f) {
  union { float f; unsigned u; } v; v.f = f;
  unsigned u = v.u;
  return (ushort)((u + 0x7fffu + ((u >> 16) & 1u)) >> 16);  // RNE
}
__device__ __forceinline__ float bf2f(ushort h) {
  union { unsigned u; float f; } v; v.u = ((unsigned)h) << 16; return v.f;
}
// pack two fp32 -> bf16x2 dword (RNE, HW v_cvt_pk when available)
__device__ __forceinline__ unsigned pk2bf(float a, float b) {
  __hip_bfloat162 h = __float22bfloat162_rn(make_float2(a, b));
  union { __hip_bfloat162 h; unsigned u; } v; v.h = h; return v.u;
}

// ---------------------------------------------------------------- convert
__global__ __launch_bounds__(256) void cvt_f32_bf16(
    const float* __restrict__ in, ushort* __restrict__ out) {
  int i = blockIdx.x * 256 + threadIdx.x;
  float4 a = ((const float4*)in)[i];
  ushort4 o;
  o.x = f2bf(a.x); o.y = f2bf(a.y); o.z = f2bf(a.z); o.w = f2bf(a.w);
  ((ushort4*)out)[i] = o;
}

// ---------------------------------------------------------------- transpose
// out[C][R](bf16) = in[R][C](fp32)^T, 64x64 tiles
__global__ __launch_bounds__(256) void transpose_cvt(
    const float* __restrict__ in, ushort* __restrict__ out, int R, int C) {
  __shared__ ushort tile[64][65];
  const int r0 = blockIdx.y * 64, c0 = blockIdx.x * 64;
  const int t = threadIdx.x;
#pragma unroll
  for (int rep = 0; rep < 16; rep++) {
    int idx = rep * 256 + t;
    int r = idx >> 6, c = idx & 63;
    tile[r][c] = f2bf(in[(size_t)(r0 + r) * C + c0 + c]);
  }
  __syncthreads();
#pragma unroll
  for (int rep = 0; rep < 16; rep++) {
    int idx = rep * 256 + t;
    int r = idx >> 6, c = idx & 63;
    out[(size_t)(c0 + r) * R + r0 + c] = tile[c][r];
  }
}

// ---------------------------------------------------------------- GEMM 256x256
// C[M][N] = A[M][K] * Bt[N][K]^T. 256x256 tile, BK=64 (2 K-halves of 32),
// 8 waves (2Mx4N). LDS = 8 half-slots (2 dbuf x 2 khalf x {A,B}, 16KiB each).
// Schedule: 8 phases per 2 K-tiles; each phase stages ONE half-slot
// (2 gld16/wave) and computes one C-quadrant (16 MFMA). vmcnt(8) at odd-phase
// tails certifies each half-slot 5 phases after issue; never drains to 0.
// SINGLE-PATH loop body (round-3 post-mortem): with 512-thread blocks, 8
// waves/CU = 2 waves/SIMD is structural, so the unified reg cap is 256/wave
// (128 VGPR + 128-reg acc). The round-2/3 duplicated tail doubled live
// ranges -> spill -> 742MB scratch writes. Tail is now handled by clamping
// prefetch tile indices (uniform SGPR min) to re-stage the last real tile
// (L2-hot, never read) so the unrolled body exists exactly once.
// EPI 0: fp32 C store. EPI 1: scatter QKV (N=6144): Q,K -> [bh][s][128],
// V -> V^T [bh][128][s] (bf16).
template <int EPI>
__global__ __launch_bounds__(512, 1) void gemm256(
    const ushort* __restrict__ A, const ushort* __restrict__ Bt,
    float* __restrict__ Cf,
    ushort* __restrict__ C0, ushort* __restrict__ C1, ushort* __restrict__ C2,
    int M, int N, int K) {
  __shared__ __align__(16) ushort As[2][2][256 * 32];
  __shared__ __align__(16) ushort Bs[2][2][256 * 32];
  const int t = threadIdx.x;
  const int lane = t & 63;
  const int w = t >> 6;
  const int l15 = lane & 15;
  const int quad = lane >> 4;
  const int m0 = blockIdx.y * 256;
  const int n0 = blockIdx.x * 256;
  const int wmB = (w >> 2) * 128;  // wave's output-row base (2 M-groups)
  const int wnB = (w & 3) * 64;    // wave's output-col base (4 N-groups)

  // staging addressing: chunk ci = w*128 + j*64 + lane; row = ci>>2;
  // src chunk = (lane&3) ^ ((row>>1)&3)  (== (lane&3)^((lane>>3)&3))
  const int cS = (lane & 3) ^ ((lane >> 3) & 3);
  const size_t aoff = (size_t)(m0 + w * 32 + (lane >> 2)) * K + cS * 8;
  const size_t boff = (size_t)(n0 + w * 32 + (lane >> 2)) * K + cS * 8;

#define STAGE_A(db, kh, tile)                                                \
  { size_t ko_ = (size_t)(tile) * 64 + (kh) * 32;                            \
    gld16(&As[db][kh][w * 1024],       A + aoff + ko_);                      \
    gld16(&As[db][kh][w * 1024 + 512], A + aoff + 16 * (size_t)K + ko_); }
#define STAGE_B(db, kh, tile)                                                \
  { size_t ko_ = (size_t)(tile) * 64 + (kh) * 32;                            \
    gld16(&Bs[db][kh][w * 1024],       Bt + boff + ko_);                     \
    gld16(&Bs[db][kh][w * 1024 + 512], Bt + boff + 16 * (size_t)K + ko_); }

#define W8 asm volatile("s_waitcnt vmcnt(8)" ::: "memory");

  floatx4 acc[8][4];
  const floatx4 zero = {0.f, 0.f, 0.f, 0.f};
#pragma unroll
  for (int i = 0; i < 8; i++)
#pragma unroll
    for (int j = 0; j < 4; j++) acc[i][j] = zero;

  bf16x8 bfr[4];

  // phase: ds-read frags | stage one half-slot | bar | lgkm0 | 16 MFMA |
  //        [cert wait] | bar
#define PH(db, kh, mh, LB, STAGE, WAIT)                                        \
  {                                                                            \
    bf16x8 af[4];                                                              \
    {                                                                          \
      const ushort* Ah = &As[db][kh][0];                                       \
      _Pragma("unroll") for (int m_ = 0; m_ < 4; ++m_) {                       \
        int r_ = wmB + ((mh) * 4 + m_) * 16 + l15;                             \
        int c_ = quad ^ ((r_ >> 1) & 3);                                       \
        af[m_] = *(const bf16x8*)&Ah[r_ * 32 + c_ * 8];                        \
      }                                                                        \
      if (LB) {                                                                \
        const ushort* Bh = &Bs[db][kh][0];                                     \
        _Pragma("unroll") for (int n_ = 0; n_ < 4; ++n_) {                     \
          int r_ = wnB + n_ * 16 + l15;                                        \
          int c_ = quad ^ ((r_ >> 1) & 3);                                     \
          bfr[n_] = *(const bf16x8*)&Bh[r_ * 32 + c_ * 8];                     \
        }                                                                      \
      }                                                                        \
    }                                                                          \
    STAGE                                                                      \
    __builtin_amdgcn_s_barrier();                                              \
    asm volatile("s_waitcnt lgkmcnt(0)" ::: "memory");                         \
    __builtin_amdgcn_sched_barrier(0);                                         \
    __builtin_amdgcn_s_setprio(1);                                             \
    _Pragma("unroll") for (int m_ = 0; m_ < 4; ++m_)                           \
      _Pragma("unroll") for (int n_ = 0; n_ < 4; ++n_)                         \
        acc[(mh) * 4 + m_][n_] = __builtin_amdgcn_mfma_f32_16x16x32_bf16(      \
            af[m_], bfr[n_], acc[(mh) * 4 + m_][n_], 0, 0, 0);                 \
    __builtin_amdgcn_s_setprio(0);                                             \
    __builtin_amdgcn_sched_barrier(0);                                         \
    WAIT                                                                       \
    __builtin_amdgcn_s_barrier();                                              \
  }

  const int NT = K >> 6;  // number of 64-wide K-tiles
  const int NI = K >> 7;  // iterations of 2 K-tiles

  // prologue: stage A(0,k0),B(0,k0),A(0,k1),B(0,k1),A(1,k0),B(1,k0);
  // certify first tile's k0 halves (drain oldest 4 of 12).
  STAGE_A(0, 0, 0);
  STAGE_B(0, 0, 0);
  STAGE_A(0, 1, 0);
  STAGE_B(0, 1, 0);
  STAGE_A(1, 0, 1);
  STAGE_B(1, 0, 1);
  W8
  __builtin_amdgcn_s_barrier();

  for (int i = 0; i < NI; ++i) {
    const int t1 = 2 * i + 1;             // always a real tile (<= NT-1)
    int t2 = 2 * i + 2, t3 = 2 * i + 3;   // clamp: last iter re-stages NT-1
    if (t2 > NT - 1) t2 = NT - 1;         // (uniform; staged data never read)
    if (t3 > NT - 1) t3 = NT - 1;
    PH(0, 0, 0, 1, STAGE_A(1, 1, t1), )
    PH(0, 0, 1, 0, STAGE_B(1, 1, t1), W8)
    PH(0, 1, 0, 1, STAGE_A(0, 0, t2), )
    PH(0, 1, 1, 0, STAGE_B(0, 0, t2), W8)
    PH(1, 0, 0, 1, STAGE_A(0, 1, t2), )
    PH(1, 0, 1, 0, STAGE_B(0, 1, t2), W8)
    PH(1, 1, 0, 1, STAGE_A(1, 0, t3), )
    PH(1, 1, 1, 0, STAGE_B(1, 0, t3), W8)
  }

#undef PH
#undef STAGE_A
#undef STAGE_B
#undef W8

  if (EPI == 0) {
#pragma unroll
    for (int m = 0; m < 8; ++m)
#pragma unroll
      for (int n = 0; n < 4; ++n)
#pragma unroll
        for (int r = 0; r < 4; ++r) {
          int row = m0 + wmB + m * 16 + quad * 4 + r;
          int col = n0 + wnB + n * 16 + l15;
          Cf[(size_t)row * N + col] = acc[m][n][r];
        }
  } else {
    // wave's 64-col span lies within one head (and one of Q/K/V)
    const int colW = n0 + wnB;
    const int sel = colW >> 11;
    const int h = (colW >> 7) & 15;
    if (sel < 2) {
      ushort* dst = (sel == 0) ? C0 : C1;
#pragma unroll
      for (int m = 0; m < 8; ++m) {
        int rowb = m0 + wmB + m * 16 + quad * 4;
        int b = rowb >> 11, s = rowb & 2047;
#pragma unroll
        for (int n = 0; n < 4; ++n) {
          int d = (colW + n * 16 + l15) & 127;
#pragma unroll
          for (int r = 0; r < 4; ++r)
            dst[((size_t)(b * 16 + h) * 2048 + (s + r)) * 128 + d] =
                f2bf(acc[m][n][r]);
        }
      }
    } else {
#pragma unroll
      for (int m = 0; m < 8; ++m) {
        int rowb = m0 + wmB + m * 16 + quad * 4;
        int b = rowb >> 11, s = rowb & 2047;
#pragma unroll
        for (int n = 0; n < 4; ++n) {
          int d = (colW + n * 16 + l15) & 127;
          ushort4 pk;
          pk.x = f2bf(acc[m][n][0]);
          pk.y = f2bf(acc[m][n][1]);
          pk.z = f2bf(acc[m][n][2]);
          pk.w = f2bf(acc[m][n][3]);
          *(ushort4*)&C2[((size_t)(b * 16 + h) * 128 + d) * 2048 + s] = pk;
        }
      }
    }
  }
}

// ---------------------------------------------------------------- RoPE
// in-place on Q and K planes: [bh][s][128]. Q additionally pre-scaled by
// (1/sqrt(128))*log2(e) so attention can use exp2 with no per-tile scaling.
__global__ __launch_bounds__(256) void rope_kernel(
    ushort* __restrict__ Q, ushort* __restrict__ Kb,
    const float* __restrict__ cosT, const float* __restrict__ sinT) {
  unsigned gid = blockIdx.x * 256u + threadIdx.x;
  int d = gid & 63;
  int s = (gid >> 6) & 2047;
  int bh = (gid >> 17) & 63;
  const bool isK = (gid >> 23) != 0;
  ushort* buf = isK ? Kb : Q;
  const float sc = isK ? 1.0f
                       : 0.08838834764831845f * 1.4426950408889634f;
  size_t base = ((size_t)bh * 2048 + s) * 128;
  float x1 = bf2f(buf[base + d]);
  float x2 = bf2f(buf[base + d + 64]);
  float c = cosT[s * 64 + d];
  float sn = sinT[s * 64 + d];
  buf[base + d] = f2bf((x1 * c - x2 * sn) * sc);
  buf[base + d + 64] = f2bf((x1 * sn + x2 * c) * sc);
}

// ---------------------------------------------------------------- attention
// flash-style causal attention, transposed-score form.
// Grid: 1-D, 2048 blocks, heavy-first: tq = 31-(bid>>6), bh = bid&63.
// Q-tile = 64 rows, 4 waves x 16 q. Per wave: S^T = K.Q^T (q = lane&15),
// per-lane scalar online softmax, P^T -> LDS (b64), O^T = V^T.P^T.
// Q [bh][s][128] (pre-scaled), K [bh][s][128], VT [bh][128][s],
// O -> [b][s][h*128+d] (bf16)
__global__ __launch_bounds__(256, 4) void attn_kernel(
    const ushort* __restrict__ Q, const ushort* __restrict__ Kb,
    const ushort* __restrict__ VT, ushort* __restrict__ O) {
  __shared__ __align__(16) ushort Ks[64 * 128];  // [k_local][d], xor(row&15)
  __shared__ __align__(16) ushort Vs[128 * 64];  // [d][s_local], xor(row&7)
  __shared__ __align__(16) ushort Ps[64 * 64];   // [q_local][k], 8-el grp xor(l15&7)
  const int t = threadIdx.x, lane = t & 63, w = t >> 6;
  const int l15 = lane & 15, quad = lane >> 4;
  const int bid = blockIdx.x;
  const int tq = 31 - (bid >> 6);   // heavy-first
  const int bh = bid & 63;
  const int q0 = tq * 64 + w * 16;
  const int qrow = q0 + l15;        // this lane's q row
  const size_t hbase = (size_t)bh * 2048 * 128;
  const float NEGINF = -__builtin_inff();

  // Q fragments (B-operand): n=q=l15, k=d contiguous 8
  bf16x8 aq[4];
#pragma unroll
  for (int kb = 0; kb < 4; kb++)
    aq[kb] = *(const bf16x8*)&Q[hbase + (size_t)qrow * 128 + kb * 32 + quad * 8];

  float m2 = NEGINF, lsum = 0.f;
  floatx4 oacc[8];  // O^T: row d = dj*16+quad*4+r, col q = l15
  const floatx4 zero = {0.f, 0.f, 0.f, 0.f};
#pragma unroll
  for (int dj = 0; dj < 8; dj++) oacc[dj] = zero;

  const int ntk = tq + 1;

  for (int tk = 0; tk < ntk; tk++) {
    __syncthreads();
#pragma unroll
    for (int it = 0; it < 4; it++) {
      int o = (w * 4 + it) * 64 + lane;
      {  // K tile: 64 rows x 128 el
        int row = o >> 4;
        int c = (o & 15) ^ (row & 15);
        gld16(&Ks[(w * 4 + it) * 512],
              Kb + hbase + (size_t)(tk * 64 + row) * 128 + c * 8);
      }
      {  // V^T tile: 128 rows x 64 el
        int row = o >> 3;
        int c = (o & 7) ^ (row & 7);
        gld16(&Vs[(w * 4 + it) * 512],
              VT + hbase + (size_t)row * 2048 + tk * 64 + c * 8);
      }
    }
    __syncthreads();

    // ---- S^T = K.Q^T : sacc[j] rows k = j*16+quad*4+r, col q = l15
    floatx4 sacc[4];
#pragma unroll
    for (int j = 0; j < 4; j++) sacc[j] = zero;
#pragma unroll
    for (int kb = 0; kb < 4; kb++) {
#pragma unroll
      for (int j = 0; j < 4; j++) {
        int row = j * 16 + l15;
        int c = (kb * 4 + quad) ^ (row & 15);
        bf16x8 kf = *(const bf16x8*)&Ks[row * 128 + c * 8];
        sacc[j] = __builtin_amdgcn_mfma_f32_16x16x32_bf16(kf, aq[kb], sacc[j],
                                                          0, 0, 0);
      }
    }

    // ---- causal mask (diagonal tile only); scores already in log2 domain
    if (tk == tq) {
#pragma unroll
      for (int j = 0; j < 4; j++)
#pragma unroll
        for (int r = 0; r < 4; r++) {
          int kcol = tk * 64 + j * 16 + quad * 4 + r;
          if (kcol > qrow) sacc[j][r] = NEGINF;
        }
    }

    // ---- per-lane scalar online softmax (row q = l15)
    float mx = sacc[0][0];
#pragma unroll
    for (int j = 0; j < 4; j++)
#pragma unroll
      for (int r = 0; r < 4; r++) mx = fmaxf(mx, sacc[j][r]);
    mx = fmaxf(mx, __shfl_xor(mx, 16));
    mx = fmaxf(mx, __shfl_xor(mx, 32));
    float mnew = fmaxf(m2, mx);
    float alpha = __builtin_exp2f(m2 - mnew);
    m2 = mnew;
    float rs = 0.f;
#pragma unroll
    for (int j = 0; j < 4; j++)
#pragma unroll
      for (int r = 0; r < 4; r++) {
        float p = __builtin_exp2f(sacc[j][r] - mnew);
        sacc[j][r] = p;
        rs += p;
      }
    rs += __shfl_xor(rs, 16);
    rs += __shfl_xor(rs, 32);
    lsum = lsum * alpha + rs;
    if (__any(alpha < 1.0f)) {
#pragma unroll
      for (int dj = 0; dj < 8; dj++) oacc[dj] *= alpha;
    }

    // ---- P^T -> LDS: row q_local = w*16+l15, 4 consecutive k per write.
    // 8-element groups swizzled: g' = g ^ (l15&7)
#pragma unroll
    for (int j = 0; j < 4; j++) {
      unsigned lo = pk2bf(sacc[j][0], sacc[j][1]);
      unsigned hi = pk2bf(sacc[j][2], sacc[j][3]);
      int g = j * 2 + (quad >> 1);
      int gp = g ^ (l15 & 7);
      uint2 pv; pv.x = lo; pv.y = hi;
      *(uint2*)&Ps[(w * 16 + l15) * 64 + gp * 8 + (quad & 1) * 4] = pv;
    }

    // ---- O^T += V^T . P^T  (same-wave Ps write->read, per-wave rows)
    bf16x8 bp[2];
#pragma unroll
    for (int kk = 0; kk < 2; kk++) {
      int g = kk * 4 + quad;
      int gp = g ^ (l15 & 7);
      bp[kk] = *(const bf16x8*)&Ps[(w * 16 + l15) * 64 + gp * 8];
    }
#pragma unroll
    for (int kk = 0; kk < 2; kk++)
#pragma unroll
      for (int dj = 0; dj < 8; dj++) {
        int rowd = dj * 16 + l15;
        int c = (kk * 4 + quad) ^ (rowd & 7);
        bf16x8 av = *(const bf16x8*)&Vs[rowd * 64 + c * 8];
        oacc[dj] = __builtin_amdgcn_mfma_f32_16x16x32_bf16(av, bp[kk], oacc[dj],
                                                           0, 0, 0);
      }
  }

  // epilogue: O^T lane holds col q = l15, rows d = dj*16+quad*4+r
  const int b = bh >> 4, h = bh & 15;
  const float rl = 1.0f / lsum;
  const size_t obase = ((size_t)(b * 2048 + qrow)) * 2048 + h * 128;
#pragma unroll
  for (int dj = 0; dj < 8; dj++) {
    ushort4 pk;
    pk.x = f2bf(oacc[dj][0] * rl);
    pk.y = f2bf(oacc[dj][1] * rl);
    pk.z = f2bf(oacc[dj][2] * rl);
    pk.w = f2bf(oacc[dj][3] * rl);
    *(ushort4*)&O[obase + dj * 16 + quad * 4] = pk;
  }
}

// ---------------------------------------------------------------- launch
// All inputs/outputs fp32 (per reference). bf16 scratch:
//   d_out[0 .. 33.5MB)  : xbf (bf16 x), dead before GEMM2 overwrites d_out
//   ws[0, 33.5M)        : wqkvT (GEMM1 only) then Ob (attn -> GEMM2)
//   ws[33.5M, 42.0M)    : woutT
//   ws[42.0M, 75.5M)    : Q   [64][2048][128]
//   ws[75.5M, 109.1M)   : K   [64][2048][128]
//   ws[109.1M, 142.6M)  : VT  [64][128][2048]
extern "C" void kernel_launch(void* const* d_in, const int* in_sizes, int n_in,
                              void* d_out, int out_size, void* d_ws, size_t ws_size,
                              hipStream_t stream) {
  const float* x    = (const float*)d_in[0];
  const float* cosT = (const float*)d_in[1];
  const float* sinT = (const float*)d_in[2];
  const float* wqkv = (const float*)d_in[3];
  const float* wout = (const float*)d_in[4];
  float* out = (float*)d_out;
  char* ws = (char*)d_ws;

  ushort* xbf   = (ushort*)d_out;                      // 8192x2048 bf16 scratch
  ushort* wqkvT = (ushort*)(ws);                       // 6144x2048
  ushort* Ob    = (ushort*)(ws);                       // 8192x2048 (after GEMM1)
  ushort* woutT = (ushort*)(ws + 33554432);            // 2048x2048
  ushort* Qb    = (ushort*)(ws + 41943040);
  ushort* Kbuf  = (ushort*)(ws + 75497472);
  ushort* VTb   = (ushort*)(ws + 109051904);

  cvt_f32_bf16<<<16384, 256, 0, stream>>>(x, xbf);
  transpose_cvt<<<dim3(96, 32), 256, 0, stream>>>(wqkv, wqkvT, 2048, 6144);
  transpose_cvt<<<dim3(32, 32), 256, 0, stream>>>(wout, woutT, 2048, 2048);
  gemm256<1><<<dim3(24, 32), 512, 0, stream>>>(xbf, wqkvT, nullptr,
                                               Qb, Kbuf, VTb, 8192, 6144, 2048);
  rope_kernel<<<65536, 256, 0, stream>>>(Qb, Kbuf, cosT, sinT);
  attn_kernel<<<2048, 256, 0, stream>>>(Qb, Kbuf, VTb, Ob);
  gemm256<0><<<dim3(8, 32), 512, 0, stream>>>(Ob, woutT, out,
                                              nullptr, nullptr, nullptr,
                                              8192, 2048, 2048);
}

// Round 5
// 600.242 us; speedup vs baseline: 1.4951x; 1.0337x over previous
//
#include <hip/hip_runtime.h>
#include <hip/hip_bf16.h>
#include <stdint.h>

typedef __bf16  bf16x8  __attribute__((ext_vector_type(8)));
typedef float   floatx4 __attribute__((ext_vector_type(4)));

typedef __attribute__((address_space(1))) void gvoid_t;
typedef __attribute__((address_space(3))) void svoid_t;

// async global->LDS, 16B per lane; lds must be wave-uniform base (HW adds lane*16)
__device__ __forceinline__ void gld16(ushort* lds, const ushort* g) {
  __builtin_amdgcn_global_load_lds((gvoid_t*)g, (svoid_t*)lds, 16, 0, 0);
}

__device__ __forceinline__ ushort f2bf(float f) {
  union { float f; unsigned u; } v; v.f = f;
  unsigned u = v.u;
  return (ushort)((u + 0x7fffu + ((u >> 16) & 1u)) >> 16);  // RNE
}
__device__ __forceinline__ float bf2f(ushort h) {
  union { unsigned u; float f; } v; v.u = ((unsigned)h) << 16; return v.f;
}
// pack two fp32 -> bf16x2 dword (RNE, HW v_cvt_pk when available)
__device__ __forceinline__ unsigned pk2bf(float a, float b) {
  __hip_bfloat162 h = __float22bfloat162_rn(make_float2(a, b));
  union { __hip_bfloat162 h; unsigned u; } v; v.h = h; return v.u;
}

// ---------------------------------------------------------------- convert
__global__ __launch_bounds__(256) void cvt_f32_bf16(
    const float* __restrict__ in, ushort* __restrict__ out) {
  int i = blockIdx.x * 256 + threadIdx.x;
  float4 a = ((const float4*)in)[i];
  ushort4 o;
  o.x = f2bf(a.x); o.y = f2bf(a.y); o.z = f2bf(a.z); o.w = f2bf(a.w);
  ((ushort4*)out)[i] = o;
}

// ---------------------------------------------------------------- transpose
// out[C][R](bf16) = in[R][C](fp32)^T, 64x64 tiles
__global__ __launch_bounds__(256) void transpose_cvt(
    const float* __restrict__ in, ushort* __restrict__ out, int R, int C) {
  __shared__ ushort tile[64][65];
  const int r0 = blockIdx.y * 64, c0 = blockIdx.x * 64;
  const int t = threadIdx.x;
#pragma unroll
  for (int rep = 0; rep < 16; rep++) {
    int idx = rep * 256 + t;
    int r = idx >> 6, c = idx & 63;
    tile[r][c] = f2bf(in[(size_t)(r0 + r) * C + c0 + c]);
  }
  __syncthreads();
#pragma unroll
  for (int rep = 0; rep < 16; rep++) {
    int idx = rep * 256 + t;
    int r = idx >> 6, c = idx & 63;
    out[(size_t)(c0 + r) * R + r0 + c] = tile[c][r];
  }
}

// ---------------------------------------------------------------- GEMM 256x256
// C[M][N] = A[M][K] * Bt[N][K]^T. 256x256 tile, BK=64 (2 K-halves of 32),
// 8 waves (2Mx4N). LDS = 8 half-slots (2 dbuf x 2 khalf x {A,B}, 16KiB each).
// ONE barrier per phase; software-pipelined operand reads:
//   barrier | [B-read if mh==0] | lgkm0 | 16 MFMA (A-frags from last phase) |
//   A-read for NEXT phase (af ping-pong) | stage 1 half-slot | vmcnt(8)
// vmcnt(8) each phase retires exactly the stage issued 4 phases earlier, so
// every slot is certified (own W8 + >=1 barrier for cross-wave stages) one
// phase before first read; WAR writes issue >=2 barriers after last read.
// Round-4 post-mortem: the old 2-barrier phase serialized ~830 cyc of
// ds_read latency + sync per phase against a 620-cyc MFMA cluster.
// Reg budget (256/wave hard cap at 8 waves/CU): acc 128 + af0/af1 32 +
// bfr 16 + addressing ~30 -> fits; WRITE_SIZE is the spill canary.
// EPI 0: fp32 C store. EPI 1: scatter QKV (N=6144): Q,K -> [bh][s][128],
// V -> V^T [bh][128][s] (bf16).
template <int EPI>
__global__ __launch_bounds__(512, 1) void gemm256(
    const ushort* __restrict__ A, const ushort* __restrict__ Bt,
    float* __restrict__ Cf,
    ushort* __restrict__ C0, ushort* __restrict__ C1, ushort* __restrict__ C2,
    int M, int N, int K) {
  __shared__ __align__(16) ushort As[2][2][256 * 32];
  __shared__ __align__(16) ushort Bs[2][2][256 * 32];
  const int t = threadIdx.x;
  const int lane = t & 63;
  const int w = t >> 6;
  const int l15 = lane & 15;
  const int quad = lane >> 4;
  const int m0 = blockIdx.y * 256;
  const int n0 = blockIdx.x * 256;
  const int wmB = (w >> 2) * 128;  // wave's output-row base (2 M-groups)
  const int wnB = (w & 3) * 64;    // wave's output-col base (4 N-groups)

  // staging addressing: chunk ci = w*128 + j*64 + lane; row = ci>>2;
  // src chunk = (lane&3) ^ ((row>>1)&3)  (== (lane&3)^((lane>>3)&3))
  const int cS = (lane & 3) ^ ((lane >> 3) & 3);
  const size_t aoff = (size_t)(m0 + w * 32 + (lane >> 2)) * K + cS * 8;
  const size_t boff = (size_t)(n0 + w * 32 + (lane >> 2)) * K + cS * 8;

  // loop-invariant LDS read pointers (mh=0 rows; mh adds 2048 ushorts;
  // slot (db,kh) adds db*16384 + kh*8192 ushorts -> offset: immediate)
  const ushort* const Ab = &As[0][0][0];
  const ushort* const Bb = &Bs[0][0][0];
  const ushort* aP[4];
  const ushort* bP[4];
#pragma unroll
  for (int m = 0; m < 4; ++m) {
    int r = wmB + m * 16 + l15;
    int c = quad ^ ((r >> 1) & 3);
    aP[m] = Ab + r * 32 + c * 8;
  }
#pragma unroll
  for (int n = 0; n < 4; ++n) {
    int r = wnB + n * 16 + l15;
    int c = quad ^ ((r >> 1) & 3);
    bP[n] = Bb + r * 32 + c * 8;
  }

#define STAGE_A(db, kh, tile)                                                \
  { size_t ko_ = (size_t)(tile) * 64 + (kh) * 32;                            \
    gld16(&As[db][kh][w * 1024],       A + aoff + ko_);                      \
    gld16(&As[db][kh][w * 1024 + 512], A + aoff + 16 * (size_t)K + ko_); }
#define STAGE_B(db, kh, tile)                                                \
  { size_t ko_ = (size_t)(tile) * 64 + (kh) * 32;                            \
    gld16(&Bs[db][kh][w * 1024],       Bt + boff + ko_);                     \
    gld16(&Bs[db][kh][w * 1024 + 512], Bt + boff + 16 * (size_t)K + ko_); }

#define LDA(AF, db, kh, mh)                                                  \
  _Pragma("unroll") for (int m_ = 0; m_ < 4; ++m_)                           \
    AF[m_] = *(const bf16x8*)(aP[m_] +                                       \
                              ((db) * 16384 + (kh) * 8192 + (mh) * 2048));
#define LDB(db, kh)                                                          \
  _Pragma("unroll") for (int n_ = 0; n_ < 4; ++n_)                           \
    bfr[n_] = *(const bf16x8*)(bP[n_] + ((db) * 16384 + (kh) * 8192));

  floatx4 acc[8][4];
  const floatx4 zero = {0.f, 0.f, 0.f, 0.f};
#pragma unroll
  for (int i = 0; i < 8; i++)
#pragma unroll
    for (int j = 0; j < 4; j++) acc[i][j] = zero;

  bf16x8 af0[4], af1[4], bfr[4];

  // phase: barrier | B-read (mh==0) | lgkm0 | MFMA(AFU) | A-read next (AFL) |
  //        stage | vmcnt(8)
#define PH(db, kh, mh, AFU, AFL, ndb, nkh, nmh, STAGE)                       \
  __builtin_amdgcn_s_barrier();                                              \
  if ((mh) == 0) { LDB(db, kh) }                                             \
  asm volatile("s_waitcnt lgkmcnt(0)" ::: "memory");                         \
  __builtin_amdgcn_sched_barrier(0);                                         \
  __builtin_amdgcn_s_setprio(1);                                             \
  _Pragma("unroll") for (int m_ = 0; m_ < 4; ++m_)                           \
    _Pragma("unroll") for (int n_ = 0; n_ < 4; ++n_)                         \
      acc[(mh) * 4 + m_][n_] = __builtin_amdgcn_mfma_f32_16x16x32_bf16(      \
          AFU[m_], bfr[n_], acc[(mh) * 4 + m_][n_], 0, 0, 0);                \
  __builtin_amdgcn_s_setprio(0);                                             \
  __builtin_amdgcn_sched_barrier(0);                                         \
  LDA(AFL, ndb, nkh, nmh)                                                    \
  STAGE                                                                      \
  asm volatile("s_waitcnt vmcnt(8)" ::: "memory");

  const int NT = K >> 6;  // number of 64-wide K-tiles
  const int NI = K >> 7;  // iterations of 2 K-tiles

  // prologue: 6 stages (12 loads); vmcnt(4) certifies the 4 (db0) slots;
  // barrier makes them block-visible; preload P0's A-frags.
  STAGE_A(0, 0, 0);
  STAGE_B(0, 0, 0);
  STAGE_A(0, 1, 0);
  STAGE_B(0, 1, 0);
  STAGE_A(1, 0, 1);
  STAGE_B(1, 0, 1);
  asm volatile("s_waitcnt vmcnt(4)" ::: "memory");
  __builtin_amdgcn_s_barrier();
  LDA(af0, 0, 0, 0)

  for (int i = 0; i < NI; ++i) {
    const int t1 = 2 * i + 1;             // always a real tile (<= NT-1)
    int t2 = 2 * i + 2, t3 = 2 * i + 3;   // clamp: last iter re-stages NT-1
    if (t2 > NT - 1) t2 = NT - 1;         // (uniform; staged data never read)
    if (t3 > NT - 1) t3 = NT - 1;
    PH(0, 0, 0, af0, af1, 0, 0, 1, STAGE_A(1, 1, t1))
    PH(0, 0, 1, af1, af0, 0, 1, 0, STAGE_B(1, 1, t1))
    PH(0, 1, 0, af0, af1, 0, 1, 1, STAGE_A(0, 0, t2))
    PH(0, 1, 1, af1, af0, 1, 0, 0, STAGE_B(0, 0, t2))
    PH(1, 0, 0, af0, af1, 1, 0, 1, STAGE_A(0, 1, t2))
    PH(1, 0, 1, af1, af0, 1, 1, 0, STAGE_B(0, 1, t2))
    PH(1, 1, 0, af0, af1, 1, 1, 1, STAGE_A(1, 0, t3))
    PH(1, 1, 1, af1, af0, 0, 0, 0, STAGE_B(1, 0, t3))
  }
  asm volatile("s_waitcnt vmcnt(0)" ::: "memory");

#undef PH
#undef LDA
#undef LDB
#undef STAGE_A
#undef STAGE_B

  if (EPI == 0) {
#pragma unroll
    for (int m = 0; m < 8; ++m)
#pragma unroll
      for (int n = 0; n < 4; ++n)
#pragma unroll
        for (int r = 0; r < 4; ++r) {
          int row = m0 + wmB + m * 16 + quad * 4 + r;
          int col = n0 + wnB + n * 16 + l15;
          Cf[(size_t)row * N + col] = acc[m][n][r];
        }
  } else {
    // wave's 64-col span lies within one head (and one of Q/K/V)
    const int colW = n0 + wnB;
    const int sel = colW >> 11;
    const int h = (colW >> 7) & 15;
    if (sel < 2) {
      ushort* dst = (sel == 0) ? C0 : C1;
#pragma unroll
      for (int m = 0; m < 8; ++m) {
        int rowb = m0 + wmB + m * 16 + quad * 4;
        int b = rowb >> 11, s = rowb & 2047;
#pragma unroll
        for (int n = 0; n < 4; ++n) {
          int d = (colW + n * 16 + l15) & 127;
#pragma unroll
          for (int r = 0; r < 4; ++r)
            dst[((size_t)(b * 16 + h) * 2048 + (s + r)) * 128 + d] =
                f2bf(acc[m][n][r]);
        }
      }
    } else {
#pragma unroll
      for (int m = 0; m < 8; ++m) {
        int rowb = m0 + wmB + m * 16 + quad * 4;
        int b = rowb >> 11, s = rowb & 2047;
#pragma unroll
        for (int n = 0; n < 4; ++n) {
          int d = (colW + n * 16 + l15) & 127;
          ushort4 pk;
          pk.x = f2bf(acc[m][n][0]);
          pk.y = f2bf(acc[m][n][1]);
          pk.z = f2bf(acc[m][n][2]);
          pk.w = f2bf(acc[m][n][3]);
          *(ushort4*)&C2[((size_t)(b * 16 + h) * 128 + d) * 2048 + s] = pk;
        }
      }
    }
  }
}

// ---------------------------------------------------------------- RoPE
// in-place on Q and K planes: [bh][s][128]. Q additionally pre-scaled by
// (1/sqrt(128))*log2(e) so attention can use exp2 with no per-tile scaling.
__global__ __launch_bounds__(256) void rope_kernel(
    ushort* __restrict__ Q, ushort* __restrict__ Kb,
    const float* __restrict__ cosT, const float* __restrict__ sinT) {
  unsigned gid = blockIdx.x * 256u + threadIdx.x;
  int d = gid & 63;
  int s = (gid >> 6) & 2047;
  int bh = (gid >> 17) & 63;
  const bool isK = (gid >> 23) != 0;
  ushort* buf = isK ? Kb : Q;
  const float sc = isK ? 1.0f
                       : 0.08838834764831845f * 1.4426950408889634f;
  size_t base = ((size_t)bh * 2048 + s) * 128;
  float x1 = bf2f(buf[base + d]);
  float x2 = bf2f(buf[base + d + 64]);
  float c = cosT[s * 64 + d];
  float sn = sinT[s * 64 + d];
  buf[base + d] = f2bf((x1 * c - x2 * sn) * sc);
  buf[base + d + 64] = f2bf((x1 * sn + x2 * c) * sc);
}

// ---------------------------------------------------------------- attention
// flash-style causal attention, transposed-score form.
// Grid: 1-D, 2048 blocks, heavy-first: tq = 31-(bid>>6), bh = bid&63.
// Q-tile = 64 rows, 4 waves x 16 q. Per wave: S^T = K.Q^T (q = lane&15),
// per-lane scalar online softmax, P^T -> LDS (b64), O^T = V^T.P^T.
// Q [bh][s][128] (pre-scaled), K [bh][s][128], VT [bh][128][s],
// O -> [b][s][h*128+d] (bf16)
__global__ __launch_bounds__(256, 4) void attn_kernel(
    const ushort* __restrict__ Q, const ushort* __restrict__ Kb,
    const ushort* __restrict__ VT, ushort* __restrict__ O) {
  __shared__ __align__(16) ushort Ks[64 * 128];  // [k_local][d], xor(row&15)
  __shared__ __align__(16) ushort Vs[128 * 64];  // [d][s_local], xor(row&7)
  __shared__ __align__(16) ushort Ps[64 * 64];   // [q_local][k], 8-el grp xor(l15&7)
  const int t = threadIdx.x, lane = t & 63, w = t >> 6;
  const int l15 = lane & 15, quad = lane >> 4;
  const int bid = blockIdx.x;
  const int tq = 31 - (bid >> 6);   // heavy-first
  const int bh = bid & 63;
  const int q0 = tq * 64 + w * 16;
  const int qrow = q0 + l15;        // this lane's q row
  const size_t hbase = (size_t)bh * 2048 * 128;
  const float NEGINF = -__builtin_inff();

  // Q fragments (B-operand): n=q=l15, k=d contiguous 8
  bf16x8 aq[4];
#pragma unroll
  for (int kb = 0; kb < 4; kb++)
    aq[kb] = *(const bf16x8*)&Q[hbase + (size_t)qrow * 128 + kb * 32 + quad * 8];

  float m2 = NEGINF, lsum = 0.f;
  floatx4 oacc[8];  // O^T: row d = dj*16+quad*4+r, col q = l15
  const floatx4 zero = {0.f, 0.f, 0.f, 0.f};
#pragma unroll
  for (int dj = 0; dj < 8; dj++) oacc[dj] = zero;

  const int ntk = tq + 1;

  for (int tk = 0; tk < ntk; tk++) {
    __syncthreads();
#pragma unroll
    for (int it = 0; it < 4; it++) {
      int o = (w * 4 + it) * 64 + lane;
      {  // K tile: 64 rows x 128 el
        int row = o >> 4;
        int c = (o & 15) ^ (row & 15);
        gld16(&Ks[(w * 4 + it) * 512],
              Kb + hbase + (size_t)(tk * 64 + row) * 128 + c * 8);
      }
      {  // V^T tile: 128 rows x 64 el
        int row = o >> 3;
        int c = (o & 7) ^ (row & 7);
        gld16(&Vs[(w * 4 + it) * 512],
              VT + hbase + (size_t)row * 2048 + tk * 64 + c * 8);
      }
    }
    __syncthreads();

    // ---- S^T = K.Q^T : sacc[j] rows k = j*16+quad*4+r, col q = l15
    floatx4 sacc[4];
#pragma unroll
    for (int j = 0; j < 4; j++) sacc[j] = zero;
#pragma unroll
    for (int kb = 0; kb < 4; kb++) {
#pragma unroll
      for (int j = 0; j < 4; j++) {
        int row = j * 16 + l15;
        int c = (kb * 4 + quad) ^ (row & 15);
        bf16x8 kf = *(const bf16x8*)&Ks[row * 128 + c * 8];
        sacc[j] = __builtin_amdgcn_mfma_f32_16x16x32_bf16(kf, aq[kb], sacc[j],
                                                          0, 0, 0);
      }
    }

    // ---- causal mask (diagonal tile only); scores already in log2 domain
    if (tk == tq) {
#pragma unroll
      for (int j = 0; j < 4; j++)
#pragma unroll
        for (int r = 0; r < 4; r++) {
          int kcol = tk * 64 + j * 16 + quad * 4 + r;
          if (kcol > qrow) sacc[j][r] = NEGINF;
        }
    }

    // ---- per-lane scalar online softmax (row q = l15)
    float mx = sacc[0][0];
#pragma unroll
    for (int j = 0; j < 4; j++)
#pragma unroll
      for (int r = 0; r < 4; r++) mx = fmaxf(mx, sacc[j][r]);
    mx = fmaxf(mx, __shfl_xor(mx, 16));
    mx = fmaxf(mx, __shfl_xor(mx, 32));
    float mnew = fmaxf(m2, mx);
    float alpha = __builtin_exp2f(m2 - mnew);
    m2 = mnew;
    float rs = 0.f;
#pragma unroll
    for (int j = 0; j < 4; j++)
#pragma unroll
      for (int r = 0; r < 4; r++) {
        float p = __builtin_exp2f(sacc[j][r] - mnew);
        sacc[j][r] = p;
        rs += p;
      }
    rs += __shfl_xor(rs, 16);
    rs += __shfl_xor(rs, 32);
    lsum = lsum * alpha + rs;
    if (__any(alpha < 1.0f)) {
#pragma unroll
      for (int dj = 0; dj < 8; dj++) oacc[dj] *= alpha;
    }

    // ---- P^T -> LDS: row q_local = w*16+l15, 4 consecutive k per write.
    // 8-element groups swizzled: g' = g ^ (l15&7)
#pragma unroll
    for (int j = 0; j < 4; j++) {
      unsigned lo = pk2bf(sacc[j][0], sacc[j][1]);
      unsigned hi = pk2bf(sacc[j][2], sacc[j][3]);
      int g = j * 2 + (quad >> 1);
      int gp = g ^ (l15 & 7);
      uint2 pv; pv.x = lo; pv.y = hi;
      *(uint2*)&Ps[(w * 16 + l15) * 64 + gp * 8 + (quad & 1) * 4] = pv;
    }

    // ---- O^T += V^T . P^T  (same-wave Ps write->read, per-wave rows)
    bf16x8 bp[2];
#pragma unroll
    for (int kk = 0; kk < 2; kk++) {
      int g = kk * 4 + quad;
      int gp = g ^ (l15 & 7);
      bp[kk] = *(const bf16x8*)&Ps[(w * 16 + l15) * 64 + gp * 8];
    }
#pragma unroll
    for (int kk = 0; kk < 2; kk++)
#pragma unroll
      for (int dj = 0; dj < 8; dj++) {
        int rowd = dj * 16 + l15;
        int c = (kk * 4 + quad) ^ (rowd & 7);
        bf16x8 av = *(const bf16x8*)&Vs[rowd * 64 + c * 8];
        oacc[dj] = __builtin_amdgcn_mfma_f32_16x16x32_bf16(av, bp[kk], oacc[dj],
                                                           0, 0, 0);
      }
  }

  // epilogue: O^T lane holds col q = l15, rows d = dj*16+quad*4+r
  const int b = bh >> 4, h = bh & 15;
  const float rl = 1.0f / lsum;
  const size_t obase = ((size_t)(b * 2048 + qrow)) * 2048 + h * 128;
#pragma unroll
  for (int dj = 0; dj < 8; dj++) {
    ushort4 pk;
    pk.x = f2bf(oacc[dj][0] * rl);
    pk.y = f2bf(oacc[dj][1] * rl);
    pk.z = f2bf(oacc[dj][2] * rl);
    pk.w = f2bf(oacc[dj][3] * rl);
    *(ushort4*)&O[obase + dj * 16 + quad * 4] = pk;
  }
}

// ---------------------------------------------------------------- launch
// All inputs/outputs fp32 (per reference). bf16 scratch:
//   d_out[0 .. 33.5MB)  : xbf (bf16 x), dead before GEMM2 overwrites d_out
//   ws[0, 33.5M)        : wqkvT (GEMM1 only) then Ob (attn -> GEMM2)
//   ws[33.5M, 42.0M)    : woutT
//   ws[42.0M, 75.5M)    : Q   [64][2048][128]
//   ws[75.5M, 109.1M)   : K   [64][2048][128]
//   ws[109.1M, 142.6M)  : VT  [64][128][2048]
extern "C" void kernel_launch(void* const* d_in, const int* in_sizes, int n_in,
                              void* d_out, int out_size, void* d_ws, size_t ws_size,
                              hipStream_t stream) {
  const float* x    = (const float*)d_in[0];
  const float* cosT = (const float*)d_in[1];
  const float* sinT = (const float*)d_in[2];
  const float* wqkv = (const float*)d_in[3];
  const float* wout = (const float*)d_in[4];
  float* out = (float*)d_out;
  char* ws = (char*)d_ws;

  ushort* xbf   = (ushort*)d_out;                      // 8192x2048 bf16 scratch
  ushort* wqkvT = (ushort*)(ws);                       // 6144x2048
  ushort* Ob    = (ushort*)(ws);                       // 8192x2048 (after GEMM1)
  ushort* woutT = (ushort*)(ws + 33554432);            // 2048x2048
  ushort* Qb    = (ushort*)(ws + 41943040);
  ushort* Kbuf  = (ushort*)(ws + 75497472);
  ushort* VTb   = (ushort*)(ws + 109051904);

  cvt_f32_bf16<<<16384, 256, 0, stream>>>(x, xbf);
  transpose_cvt<<<dim3(96, 32), 256, 0, stream>>>(wqkv, wqkvT, 2048, 6144);
  transpose_cvt<<<dim3(32, 32), 256, 0, stream>>>(wout, woutT, 2048, 2048);
  gemm256<1><<<dim3(24, 32), 512, 0, stream>>>(xbf, wqkvT, nullptr,
                                               Qb, Kbuf, VTb, 8192, 6144, 2048);
  rope_kernel<<<65536, 256, 0, stream>>>(Qb, Kbuf, cosT, sinT);
  attn_kernel<<<2048, 256, 0, stream>>>(Qb, Kbuf, VTb, Ob);
  gemm256<0><<<dim3(8, 32), 512, 0, stream>>>(Ob, woutT, out,
                                              nullptr, nullptr, nullptr,
                                              8192, 2048, 2048);
}

// Round 6
// 587.490 us; speedup vs baseline: 1.5276x; 1.0217x over previous
//
#include <hip/hip_runtime.h>
#include <hip/hip_bf16.h>
#include <stdint.h>

typedef __bf16  bf16x8  __attribute__((ext_vector_type(8)));
typedef float   floatx4 __attribute__((ext_vector_type(4)));

typedef __attribute__((address_space(1))) void gvoid_t;
typedef __attribute__((address_space(3))) void svoid_t;

// async global->LDS, 16B per lane; lds must be wave-uniform base (HW adds lane*16)
__device__ __forceinline__ void gld16(ushort* lds, const ushort* g) {
  __builtin_amdgcn_global_load_lds((gvoid_t*)g, (svoid_t*)lds, 16, 0, 0);
}

__device__ __forceinline__ ushort f2bf(float f) {
  union { float f; unsigned u; } v; v.f = f;
  unsigned u = v.u;
  return (ushort)((u + 0x7fffu + ((u >> 16) & 1u)) >> 16);  // RNE
}
__device__ __forceinline__ float bf2f(ushort h) {
  union { unsigned u; float f; } v; v.u = ((unsigned)h) << 16; return v.f;
}
// pack two fp32 -> bf16x2 dword (RNE, HW v_cvt_pk when available)
__device__ __forceinline__ unsigned pk2bf(float a, float b) {
  __hip_bfloat162 h = __float22bfloat162_rn(make_float2(a, b));
  union { __hip_bfloat162 h; unsigned u; } v; v.h = h; return v.u;
}

// ---------------------------------------------------------------- convert
__global__ __launch_bounds__(256) void cvt_f32_bf16(
    const float* __restrict__ in, ushort* __restrict__ out) {
  int i = blockIdx.x * 256 + threadIdx.x;
  float4 a = ((const float4*)in)[i];
  ushort4 o;
  o.x = f2bf(a.x); o.y = f2bf(a.y); o.z = f2bf(a.z); o.w = f2bf(a.w);
  ((ushort4*)out)[i] = o;
}

// ---------------------------------------------------------------- transpose
// out[C][R](bf16) = in[R][C](fp32)^T, 64x64 tiles
__global__ __launch_bounds__(256) void transpose_cvt(
    const float* __restrict__ in, ushort* __restrict__ out, int R, int C) {
  __shared__ ushort tile[64][65];
  const int r0 = blockIdx.y * 64, c0 = blockIdx.x * 64;
  const int t = threadIdx.x;
#pragma unroll
  for (int rep = 0; rep < 16; rep++) {
    int idx = rep * 256 + t;
    int r = idx >> 6, c = idx & 63;
    tile[r][c] = f2bf(in[(size_t)(r0 + r) * C + c0 + c]);
  }
  __syncthreads();
#pragma unroll
  for (int rep = 0; rep < 16; rep++) {
    int idx = rep * 256 + t;
    int r = idx >> 6, c = idx & 63;
    out[(size_t)(c0 + r) * R + r0 + c] = tile[c][r];
  }
}

// ---------------------------------------------------------------- GEMM 256x256
// (unchanged from round 5 — verified at 208 us / MfmaUtil 43%)
// C[M][N] = A[M][K] * Bt[N][K]^T. 256x256 tile, BK=64 (2 K-halves of 32),
// 8 waves (2Mx4N). LDS = 8 half-slots (2 dbuf x 2 khalf x {A,B}, 16KiB each).
// ONE barrier per phase; software-pipelined operand reads.
template <int EPI>
__global__ __launch_bounds__(512, 1) void gemm256(
    const ushort* __restrict__ A, const ushort* __restrict__ Bt,
    float* __restrict__ Cf,
    ushort* __restrict__ C0, ushort* __restrict__ C1, ushort* __restrict__ C2,
    int M, int N, int K) {
  __shared__ __align__(16) ushort As[2][2][256 * 32];
  __shared__ __align__(16) ushort Bs[2][2][256 * 32];
  const int t = threadIdx.x;
  const int lane = t & 63;
  const int w = t >> 6;
  const int l15 = lane & 15;
  const int quad = lane >> 4;
  const int m0 = blockIdx.y * 256;
  const int n0 = blockIdx.x * 256;
  const int wmB = (w >> 2) * 128;  // wave's output-row base (2 M-groups)
  const int wnB = (w & 3) * 64;    // wave's output-col base (4 N-groups)

  const int cS = (lane & 3) ^ ((lane >> 3) & 3);
  const size_t aoff = (size_t)(m0 + w * 32 + (lane >> 2)) * K + cS * 8;
  const size_t boff = (size_t)(n0 + w * 32 + (lane >> 2)) * K + cS * 8;

  const ushort* const Ab = &As[0][0][0];
  const ushort* const Bb = &Bs[0][0][0];
  const ushort* aP[4];
  const ushort* bP[4];
#pragma unroll
  for (int m = 0; m < 4; ++m) {
    int r = wmB + m * 16 + l15;
    int c = quad ^ ((r >> 1) & 3);
    aP[m] = Ab + r * 32 + c * 8;
  }
#pragma unroll
  for (int n = 0; n < 4; ++n) {
    int r = wnB + n * 16 + l15;
    int c = quad ^ ((r >> 1) & 3);
    bP[n] = Bb + r * 32 + c * 8;
  }

#define STAGE_A(db, kh, tile)                                                \
  { size_t ko_ = (size_t)(tile) * 64 + (kh) * 32;                            \
    gld16(&As[db][kh][w * 1024],       A + aoff + ko_);                      \
    gld16(&As[db][kh][w * 1024 + 512], A + aoff + 16 * (size_t)K + ko_); }
#define STAGE_B(db, kh, tile)                                                \
  { size_t ko_ = (size_t)(tile) * 64 + (kh) * 32;                            \
    gld16(&Bs[db][kh][w * 1024],       Bt + boff + ko_);                     \
    gld16(&Bs[db][kh][w * 1024 + 512], Bt + boff + 16 * (size_t)K + ko_); }

#define LDA(AF, db, kh, mh)                                                  \
  _Pragma("unroll") for (int m_ = 0; m_ < 4; ++m_)                           \
    AF[m_] = *(const bf16x8*)(aP[m_] +                                       \
                              ((db) * 16384 + (kh) * 8192 + (mh) * 2048));
#define LDB(db, kh)                                                          \
  _Pragma("unroll") for (int n_ = 0; n_ < 4; ++n_)                           \
    bfr[n_] = *(const bf16x8*)(bP[n_] + ((db) * 16384 + (kh) * 8192));

  floatx4 acc[8][4];
  const floatx4 zero = {0.f, 0.f, 0.f, 0.f};
#pragma unroll
  for (int i = 0; i < 8; i++)
#pragma unroll
    for (int j = 0; j < 4; j++) acc[i][j] = zero;

  bf16x8 af0[4], af1[4], bfr[4];

#define PH(db, kh, mh, AFU, AFL, ndb, nkh, nmh, STAGE)                       \
  __builtin_amdgcn_s_barrier();                                              \
  if ((mh) == 0) { LDB(db, kh) }                                             \
  asm volatile("s_waitcnt lgkmcnt(0)" ::: "memory");                         \
  __builtin_amdgcn_sched_barrier(0);                                         \
  __builtin_amdgcn_s_setprio(1);                                             \
  _Pragma("unroll") for (int m_ = 0; m_ < 4; ++m_)                           \
    _Pragma("unroll") for (int n_ = 0; n_ < 4; ++n_)                         \
      acc[(mh) * 4 + m_][n_] = __builtin_amdgcn_mfma_f32_16x16x32_bf16(      \
          AFU[m_], bfr[n_], acc[(mh) * 4 + m_][n_], 0, 0, 0);                \
  __builtin_amdgcn_s_setprio(0);                                             \
  __builtin_amdgcn_sched_barrier(0);                                         \
  LDA(AFL, ndb, nkh, nmh)                                                    \
  STAGE                                                                      \
  asm volatile("s_waitcnt vmcnt(8)" ::: "memory");

  const int NT = K >> 6;  // number of 64-wide K-tiles
  const int NI = K >> 7;  // iterations of 2 K-tiles

  STAGE_A(0, 0, 0);
  STAGE_B(0, 0, 0);
  STAGE_A(0, 1, 0);
  STAGE_B(0, 1, 0);
  STAGE_A(1, 0, 1);
  STAGE_B(1, 0, 1);
  asm volatile("s_waitcnt vmcnt(4)" ::: "memory");
  __builtin_amdgcn_s_barrier();
  LDA(af0, 0, 0, 0)

  for (int i = 0; i < NI; ++i) {
    const int t1 = 2 * i + 1;             // always a real tile (<= NT-1)
    int t2 = 2 * i + 2, t3 = 2 * i + 3;   // clamp: last iter re-stages NT-1
    if (t2 > NT - 1) t2 = NT - 1;         // (uniform; staged data never read)
    if (t3 > NT - 1) t3 = NT - 1;
    PH(0, 0, 0, af0, af1, 0, 0, 1, STAGE_A(1, 1, t1))
    PH(0, 0, 1, af1, af0, 0, 1, 0, STAGE_B(1, 1, t1))
    PH(0, 1, 0, af0, af1, 0, 1, 1, STAGE_A(0, 0, t2))
    PH(0, 1, 1, af1, af0, 1, 0, 0, STAGE_B(0, 0, t2))
    PH(1, 0, 0, af0, af1, 1, 0, 1, STAGE_A(0, 1, t2))
    PH(1, 0, 1, af1, af0, 1, 1, 0, STAGE_B(0, 1, t2))
    PH(1, 1, 0, af0, af1, 1, 1, 1, STAGE_A(1, 0, t3))
    PH(1, 1, 1, af1, af0, 0, 0, 0, STAGE_B(1, 0, t3))
  }
  asm volatile("s_waitcnt vmcnt(0)" ::: "memory");

#undef PH
#undef LDA
#undef LDB
#undef STAGE_A
#undef STAGE_B

  if (EPI == 0) {
#pragma unroll
    for (int m = 0; m < 8; ++m)
#pragma unroll
      for (int n = 0; n < 4; ++n)
#pragma unroll
        for (int r = 0; r < 4; ++r) {
          int row = m0 + wmB + m * 16 + quad * 4 + r;
          int col = n0 + wnB + n * 16 + l15;
          Cf[(size_t)row * N + col] = acc[m][n][r];
        }
  } else {
    const int colW = n0 + wnB;
    const int sel = colW >> 11;
    const int h = (colW >> 7) & 15;
    if (sel < 2) {
      ushort* dst = (sel == 0) ? C0 : C1;
#pragma unroll
      for (int m = 0; m < 8; ++m) {
        int rowb = m0 + wmB + m * 16 + quad * 4;
        int b = rowb >> 11, s = rowb & 2047;
#pragma unroll
        for (int n = 0; n < 4; ++n) {
          int d = (colW + n * 16 + l15) & 127;
#pragma unroll
          for (int r = 0; r < 4; ++r)
            dst[((size_t)(b * 16 + h) * 2048 + (s + r)) * 128 + d] =
                f2bf(acc[m][n][r]);
        }
      }
    } else {
#pragma unroll
      for (int m = 0; m < 8; ++m) {
        int rowb = m0 + wmB + m * 16 + quad * 4;
        int b = rowb >> 11, s = rowb & 2047;
#pragma unroll
        for (int n = 0; n < 4; ++n) {
          int d = (colW + n * 16 + l15) & 127;
          ushort4 pk;
          pk.x = f2bf(acc[m][n][0]);
          pk.y = f2bf(acc[m][n][1]);
          pk.z = f2bf(acc[m][n][2]);
          pk.w = f2bf(acc[m][n][3]);
          *(ushort4*)&C2[((size_t)(b * 16 + h) * 128 + d) * 2048 + s] = pk;
        }
      }
    }
  }
}

// ---------------------------------------------------------------- RoPE
// in-place on Q and K planes: [bh][s][128]. Q additionally pre-scaled by
// (1/sqrt(128))*log2(e) so attention can use exp2 with no per-tile scaling.
__global__ __launch_bounds__(256) void rope_kernel(
    ushort* __restrict__ Q, ushort* __restrict__ Kb,
    const float* __restrict__ cosT, const float* __restrict__ sinT) {
  unsigned gid = blockIdx.x * 256u + threadIdx.x;
  int d = gid & 63;
  int s = (gid >> 6) & 2047;
  int bh = (gid >> 17) & 63;
  const bool isK = (gid >> 23) != 0;
  ushort* buf = isK ? Kb : Q;
  const float sc = isK ? 1.0f
                       : 0.08838834764831845f * 1.4426950408889634f;
  size_t base = ((size_t)bh * 2048 + s) * 128;
  float x1 = bf2f(buf[base + d]);
  float x2 = bf2f(buf[base + d + 64]);
  float c = cosT[s * 64 + d];
  float sn = sinT[s * 64 + d];
  buf[base + d] = f2bf((x1 * c - x2 * sn) * sc);
  buf[base + d + 64] = f2bf((x1 * sn + x2 * c) * sc);
}

// ---------------------------------------------------------------- attention
// flash-style causal attention, transposed-score form, Q-tile = 128 rows.
// Grid: 1024 blocks (16 q-groups x 64 bh), heavy-first: tq = 15-(bid>>6).
// 8 waves x 16 q each; K/V double-buffered in LDS, prefetch-before-compute
// (stage tile tk+1, compute tk, vmcnt(0)+barrier) -> load latency hidden,
// one barrier per tile. Per-wave inner structure identical to the verified
// 4-wave kernel. LDS = 2*(16K+16K) + Ps 16K = 80KiB -> 2 blocks/CU.
// Q [bh][s][128] (pre-scaled), K [bh][s][128], VT [bh][128][s],
// O -> [b][s][h*128+d] (bf16)
__global__ __launch_bounds__(512, 4) void attn_kernel(
    const ushort* __restrict__ Q, const ushort* __restrict__ Kb,
    const ushort* __restrict__ VT, ushort* __restrict__ O) {
  __shared__ __align__(16) ushort Ks[2][64 * 128];  // [k_local][d], xor(row&15)
  __shared__ __align__(16) ushort Vs[2][128 * 64];  // [d][s_local], xor(row&7)
  __shared__ __align__(16) ushort Ps[128 * 64];     // [q_local][k]
  const int t = threadIdx.x, lane = t & 63, w = t >> 6;  // w 0..7
  const int l15 = lane & 15, quad = lane >> 4;
  const int bid = blockIdx.x;
  const int tq = 15 - (bid >> 6);   // heavy-first, 128-row q-tiles
  const int bh = bid & 63;
  const int qrow = tq * 128 + w * 16 + l15;  // this lane's q row
  const size_t hbase = (size_t)bh * 2048 * 128;
  const float NEGINF = -__builtin_inff();

  // staging source bases (per-lane, tile-invariant). Per wave: 2 K + 2 V gld16.
  // K chunk o = (w*2+it)*64+lane: row = w*8+it*4+quad, c = l15^(row&15)
  const int kr0 = w * 8 + quad, kr1 = w * 8 + 4 + quad;
  const ushort* kS0 = Kb + hbase + (size_t)kr0 * 128 + (l15 ^ (kr0 & 15)) * 8;
  const ushort* kS1 = Kb + hbase + (size_t)kr1 * 128 + (l15 ^ (kr1 & 15)) * 8;
  // V chunk o: row = w*16+it*8+(lane>>3), c = (lane&7)^(row&7)
  const int vr0 = w * 16 + (lane >> 3), vr1 = w * 16 + 8 + (lane >> 3);
  const ushort* vS0 = VT + hbase + (size_t)vr0 * 2048 + ((lane & 7) ^ (vr0 & 7)) * 8;
  const ushort* vS1 = VT + hbase + (size_t)vr1 * 2048 + ((lane & 7) ^ (vr1 & 7)) * 8;

  // Q fragments (B-operand): n=q=l15, k=d contiguous 8
  bf16x8 aq[4];
#pragma unroll
  for (int kb = 0; kb < 4; kb++)
    aq[kb] = *(const bf16x8*)&Q[hbase + (size_t)qrow * 128 + kb * 32 + quad * 8];

  float m2 = NEGINF, lsum = 0.f;
  floatx4 oacc[8];  // O^T: row d = dj*16+quad*4+r, col q = l15
  const floatx4 zero = {0.f, 0.f, 0.f, 0.f};
#pragma unroll
  for (int dj = 0; dj < 8; dj++) oacc[dj] = zero;

  const int ntk = 2 * tq + 2;  // 64-wide K-tiles

#define STAGE(b, tile)                                                \
  { gld16(&Ks[b][(w * 2 + 0) * 512], kS0 + (size_t)(tile) * 8192);    \
    gld16(&Ks[b][(w * 2 + 1) * 512], kS1 + (size_t)(tile) * 8192);    \
    gld16(&Vs[b][(w * 2 + 0) * 512], vS0 + (size_t)(tile) * 64);      \
    gld16(&Vs[b][(w * 2 + 1) * 512], vS1 + (size_t)(tile) * 64); }

  // prologue: stage tile 0 into buf 0
  STAGE(0, 0)
  asm volatile("s_waitcnt vmcnt(0)" ::: "memory");
  __builtin_amdgcn_s_barrier();

  int cur = 0;
  for (int tk = 0; tk < ntk; tk++) {
    // prefetch next tile into the other buffer (its readers finished before
    // the previous trailing barrier); latency hides under this tile's compute
    if (tk + 1 < ntk) STAGE(cur ^ 1, tk + 1)
    const ushort* Kc = &Ks[cur][0];
    const ushort* Vc = &Vs[cur][0];

    // ---- S^T = K.Q^T : sacc[j] rows k = j*16+quad*4+r, col q = l15
    floatx4 sacc[4];
#pragma unroll
    for (int j = 0; j < 4; j++) sacc[j] = zero;
#pragma unroll
    for (int kb = 0; kb < 4; kb++) {
#pragma unroll
      for (int j = 0; j < 4; j++) {
        int row = j * 16 + l15;
        int c = (kb * 4 + quad) ^ (row & 15);
        bf16x8 kf = *(const bf16x8*)&Kc[row * 128 + c * 8];
        sacc[j] = __builtin_amdgcn_mfma_f32_16x16x32_bf16(kf, aq[kb], sacc[j],
                                                          0, 0, 0);
      }
    }

    // ---- causal mask (last two tiles only; scores already in log2 domain)
    if (tk >= ntk - 2) {
#pragma unroll
      for (int j = 0; j < 4; j++)
#pragma unroll
        for (int r = 0; r < 4; r++) {
          int kcol = tk * 64 + j * 16 + quad * 4 + r;
          if (kcol > qrow) sacc[j][r] = NEGINF;
        }
    }

    // ---- per-lane scalar online softmax (row q = l15)
    float mx = sacc[0][0];
#pragma unroll
    for (int j = 0; j < 4; j++)
#pragma unroll
      for (int r = 0; r < 4; r++) mx = fmaxf(mx, sacc[j][r]);
    mx = fmaxf(mx, __shfl_xor(mx, 16));
    mx = fmaxf(mx, __shfl_xor(mx, 32));
    float mnew = fmaxf(m2, mx);
    float alpha = __builtin_exp2f(m2 - mnew);
    m2 = mnew;
    float rs = 0.f;
#pragma unroll
    for (int j = 0; j < 4; j++)
#pragma unroll
      for (int r = 0; r < 4; r++) {
        float p = __builtin_exp2f(sacc[j][r] - mnew);
        sacc[j][r] = p;
        rs += p;
      }
    rs += __shfl_xor(rs, 16);
    rs += __shfl_xor(rs, 32);
    lsum = lsum * alpha + rs;
    if (__any(alpha < 1.0f)) {
#pragma unroll
      for (int dj = 0; dj < 8; dj++) oacc[dj] *= alpha;
    }

    // ---- P^T -> LDS: row q_local = w*16+l15, 4 consecutive k per write.
    // 8-element groups swizzled: g' = g ^ (l15&7)
#pragma unroll
    for (int j = 0; j < 4; j++) {
      unsigned lo = pk2bf(sacc[j][0], sacc[j][1]);
      unsigned hi = pk2bf(sacc[j][2], sacc[j][3]);
      int g = j * 2 + (quad >> 1);
      int gp = g ^ (l15 & 7);
      uint2 pv; pv.x = lo; pv.y = hi;
      *(uint2*)&Ps[(w * 16 + l15) * 64 + gp * 8 + (quad & 1) * 4] = pv;
    }

    // ---- O^T += V^T . P^T  (same-wave Ps write->read, per-wave rows)
    bf16x8 bp[2];
#pragma unroll
    for (int kk = 0; kk < 2; kk++) {
      int g = kk * 4 + quad;
      int gp = g ^ (l15 & 7);
      bp[kk] = *(const bf16x8*)&Ps[(w * 16 + l15) * 64 + gp * 8];
    }
#pragma unroll
    for (int kk = 0; kk < 2; kk++)
#pragma unroll
      for (int dj = 0; dj < 8; dj++) {
        int rowd = dj * 16 + l15;
        int c = (kk * 4 + quad) ^ (rowd & 7);
        bf16x8 av = *(const bf16x8*)&Vc[rowd * 64 + c * 8];
        oacc[dj] = __builtin_amdgcn_mfma_f32_16x16x32_bf16(av, bp[kk], oacc[dj],
                                                           0, 0, 0);
      }

    // ---- own prefetch landed (issued ~2.5k cycles ago); publish to block
    asm volatile("s_waitcnt vmcnt(0)" ::: "memory");
    __builtin_amdgcn_s_barrier();
    cur ^= 1;
  }
#undef STAGE

  // epilogue: O^T lane holds col q = l15, rows d = dj*16+quad*4+r
  const int b = bh >> 4, h = bh & 15;
  const float rl = 1.0f / lsum;
  const size_t obase = ((size_t)(b * 2048 + qrow)) * 2048 + h * 128;
#pragma unroll
  for (int dj = 0; dj < 8; dj++) {
    ushort4 pk;
    pk.x = f2bf(oacc[dj][0] * rl);
    pk.y = f2bf(oacc[dj][1] * rl);
    pk.z = f2bf(oacc[dj][2] * rl);
    pk.w = f2bf(oacc[dj][3] * rl);
    *(ushort4*)&O[obase + dj * 16 + quad * 4] = pk;
  }
}

// ---------------------------------------------------------------- launch
// All inputs/outputs fp32 (per reference). bf16 scratch:
//   d_out[0 .. 33.5MB)  : xbf (bf16 x), dead before GEMM2 overwrites d_out
//   ws[0, 33.5M)        : wqkvT (GEMM1 only) then Ob (attn -> GEMM2)
//   ws[33.5M, 42.0M)    : woutT
//   ws[42.0M, 75.5M)    : Q   [64][2048][128]
//   ws[75.5M, 109.1M)   : K   [64][2048][128]
//   ws[109.1M, 142.6M)  : VT  [64][128][2048]
extern "C" void kernel_launch(void* const* d_in, const int* in_sizes, int n_in,
                              void* d_out, int out_size, void* d_ws, size_t ws_size,
                              hipStream_t stream) {
  const float* x    = (const float*)d_in[0];
  const float* cosT = (const float*)d_in[1];
  const float* sinT = (const float*)d_in[2];
  const float* wqkv = (const float*)d_in[3];
  const float* wout = (const float*)d_in[4];
  float* out = (float*)d_out;
  char* ws = (char*)d_ws;

  ushort* xbf   = (ushort*)d_out;                      // 8192x2048 bf16 scratch
  ushort* wqkvT = (ushort*)(ws);                       // 6144x2048
  ushort* Ob    = (ushort*)(ws);                       // 8192x2048 (after GEMM1)
  ushort* woutT = (ushort*)(ws + 33554432);            // 2048x2048
  ushort* Qb    = (ushort*)(ws + 41943040);
  ushort* Kbuf  = (ushort*)(ws + 75497472);
  ushort* VTb   = (ushort*)(ws + 109051904);

  cvt_f32_bf16<<<16384, 256, 0, stream>>>(x, xbf);
  transpose_cvt<<<dim3(96, 32), 256, 0, stream>>>(wqkv, wqkvT, 2048, 6144);
  transpose_cvt<<<dim3(32, 32), 256, 0, stream>>>(wout, woutT, 2048, 2048);
  gemm256<1><<<dim3(24, 32), 512, 0, stream>>>(xbf, wqkvT, nullptr,
                                               Qb, Kbuf, VTb, 8192, 6144, 2048);
  rope_kernel<<<65536, 256, 0, stream>>>(Qb, Kbuf, cosT, sinT);
  attn_kernel<<<1024, 512, 0, stream>>>(Qb, Kbuf, VTb, Ob);
  gemm256<0><<<dim3(8, 32), 512, 0, stream>>>(Ob, woutT, out,
                                              nullptr, nullptr, nullptr,
                                              8192, 2048, 2048);
}

// Round 7
// 586.616 us; speedup vs baseline: 1.5298x; 1.0015x over previous
//
#include <hip/hip_runtime.h>
#include <hip/hip_bf16.h>
#include <stdint.h>

typedef __bf16  bf16x8  __attribute__((ext_vector_type(8)));
typedef float   floatx4 __attribute__((ext_vector_type(4)));

typedef __attribute__((address_space(1))) void gvoid_t;
typedef __attribute__((address_space(3))) void svoid_t;

// async global->LDS, 16B per lane; lds must be wave-uniform base (HW adds lane*16)
__device__ __forceinline__ void gld16(ushort* lds, const ushort* g) {
  __builtin_amdgcn_global_load_lds((gvoid_t*)g, (svoid_t*)lds, 16, 0, 0);
}

__device__ __forceinline__ ushort f2bf(float f) {
  union { float f; unsigned u; } v; v.f = f;
  unsigned u = v.u;
  return (ushort)((u + 0x7fffu + ((u >> 16) & 1u)) >> 16);  // RNE
}
__device__ __forceinline__ float bf2f(ushort h) {
  union { unsigned u; float f; } v; v.u = ((unsigned)h) << 16; return v.f;
}
// pack two fp32 -> bf16x2 dword (RNE, HW v_cvt_pk when available)
__device__ __forceinline__ unsigned pk2bf(float a, float b) {
  __hip_bfloat162 h = __float22bfloat162_rn(make_float2(a, b));
  union { __hip_bfloat162 h; unsigned u; } v; v.h = h; return v.u;
}

// ---------------------------------------------------------------- convert
__global__ __launch_bounds__(256) void cvt_f32_bf16(
    const float* __restrict__ in, ushort* __restrict__ out) {
  int i = blockIdx.x * 256 + threadIdx.x;
  float4 a = ((const float4*)in)[i];
  ushort4 o;
  o.x = f2bf(a.x); o.y = f2bf(a.y); o.z = f2bf(a.z); o.w = f2bf(a.w);
  ((ushort4*)out)[i] = o;
}

// ---------------------------------------------------------------- transpose
// out[C][R](bf16) = in[R][C](fp32)^T, 64x64 tiles
__global__ __launch_bounds__(256) void transpose_cvt(
    const float* __restrict__ in, ushort* __restrict__ out, int R, int C) {
  __shared__ ushort tile[64][65];
  const int r0 = blockIdx.y * 64, c0 = blockIdx.x * 64;
  const int t = threadIdx.x;
#pragma unroll
  for (int rep = 0; rep < 16; rep++) {
    int idx = rep * 256 + t;
    int r = idx >> 6, c = idx & 63;
    tile[r][c] = f2bf(in[(size_t)(r0 + r) * C + c0 + c]);
  }
  __syncthreads();
#pragma unroll
  for (int rep = 0; rep < 16; rep++) {
    int idx = rep * 256 + t;
    int r = idx >> 6, c = idx & 63;
    out[(size_t)(c0 + r) * R + r0 + c] = tile[c][r];
  }
}

// ---------------------------------------------------------------- GEMM 256x256
// (unchanged — verified at 207 us / MfmaUtil 43%)
template <int EPI>
__global__ __launch_bounds__(512, 1) void gemm256(
    const ushort* __restrict__ A, const ushort* __restrict__ Bt,
    float* __restrict__ Cf,
    ushort* __restrict__ C0, ushort* __restrict__ C1, ushort* __restrict__ C2,
    int M, int N, int K) {
  __shared__ __align__(16) ushort As[2][2][256 * 32];
  __shared__ __align__(16) ushort Bs[2][2][256 * 32];
  const int t = threadIdx.x;
  const int lane = t & 63;
  const int w = t >> 6;
  const int l15 = lane & 15;
  const int quad = lane >> 4;
  const int m0 = blockIdx.y * 256;
  const int n0 = blockIdx.x * 256;
  const int wmB = (w >> 2) * 128;  // wave's output-row base (2 M-groups)
  const int wnB = (w & 3) * 64;    // wave's output-col base (4 N-groups)

  const int cS = (lane & 3) ^ ((lane >> 3) & 3);
  const size_t aoff = (size_t)(m0 + w * 32 + (lane >> 2)) * K + cS * 8;
  const size_t boff = (size_t)(n0 + w * 32 + (lane >> 2)) * K + cS * 8;

  const ushort* const Ab = &As[0][0][0];
  const ushort* const Bb = &Bs[0][0][0];
  const ushort* aP[4];
  const ushort* bP[4];
#pragma unroll
  for (int m = 0; m < 4; ++m) {
    int r = wmB + m * 16 + l15;
    int c = quad ^ ((r >> 1) & 3);
    aP[m] = Ab + r * 32 + c * 8;
  }
#pragma unroll
  for (int n = 0; n < 4; ++n) {
    int r = wnB + n * 16 + l15;
    int c = quad ^ ((r >> 1) & 3);
    bP[n] = Bb + r * 32 + c * 8;
  }

#define STAGE_A(db, kh, tile)                                                \
  { size_t ko_ = (size_t)(tile) * 64 + (kh) * 32;                            \
    gld16(&As[db][kh][w * 1024],       A + aoff + ko_);                      \
    gld16(&As[db][kh][w * 1024 + 512], A + aoff + 16 * (size_t)K + ko_); }
#define STAGE_B(db, kh, tile)                                                \
  { size_t ko_ = (size_t)(tile) * 64 + (kh) * 32;                            \
    gld16(&Bs[db][kh][w * 1024],       Bt + boff + ko_);                     \
    gld16(&Bs[db][kh][w * 1024 + 512], Bt + boff + 16 * (size_t)K + ko_); }

#define LDA(AF, db, kh, mh)                                                  \
  _Pragma("unroll") for (int m_ = 0; m_ < 4; ++m_)                           \
    AF[m_] = *(const bf16x8*)(aP[m_] +                                       \
                              ((db) * 16384 + (kh) * 8192 + (mh) * 2048));
#define LDB(db, kh)                                                          \
  _Pragma("unroll") for (int n_ = 0; n_ < 4; ++n_)                           \
    bfr[n_] = *(const bf16x8*)(bP[n_] + ((db) * 16384 + (kh) * 8192));

  floatx4 acc[8][4];
  const floatx4 zero = {0.f, 0.f, 0.f, 0.f};
#pragma unroll
  for (int i = 0; i < 8; i++)
#pragma unroll
    for (int j = 0; j < 4; j++) acc[i][j] = zero;

  bf16x8 af0[4], af1[4], bfr[4];

#define PH(db, kh, mh, AFU, AFL, ndb, nkh, nmh, STAGE)                       \
  __builtin_amdgcn_s_barrier();                                              \
  if ((mh) == 0) { LDB(db, kh) }                                             \
  asm volatile("s_waitcnt lgkmcnt(0)" ::: "memory");                         \
  __builtin_amdgcn_sched_barrier(0);                                         \
  __builtin_amdgcn_s_setprio(1);                                             \
  _Pragma("unroll") for (int m_ = 0; m_ < 4; ++m_)                           \
    _Pragma("unroll") for (int n_ = 0; n_ < 4; ++n_)                         \
      acc[(mh) * 4 + m_][n_] = __builtin_amdgcn_mfma_f32_16x16x32_bf16(      \
          AFU[m_], bfr[n_], acc[(mh) * 4 + m_][n_], 0, 0, 0);                \
  __builtin_amdgcn_s_setprio(0);                                             \
  __builtin_amdgcn_sched_barrier(0);                                         \
  LDA(AFL, ndb, nkh, nmh)                                                    \
  STAGE                                                                      \
  asm volatile("s_waitcnt vmcnt(8)" ::: "memory");

  const int NT = K >> 6;  // number of 64-wide K-tiles
  const int NI = K >> 7;  // iterations of 2 K-tiles

  STAGE_A(0, 0, 0);
  STAGE_B(0, 0, 0);
  STAGE_A(0, 1, 0);
  STAGE_B(0, 1, 0);
  STAGE_A(1, 0, 1);
  STAGE_B(1, 0, 1);
  asm volatile("s_waitcnt vmcnt(4)" ::: "memory");
  __builtin_amdgcn_s_barrier();
  LDA(af0, 0, 0, 0)

  for (int i = 0; i < NI; ++i) {
    const int t1 = 2 * i + 1;             // always a real tile (<= NT-1)
    int t2 = 2 * i + 2, t3 = 2 * i + 3;   // clamp: last iter re-stages NT-1
    if (t2 > NT - 1) t2 = NT - 1;         // (uniform; staged data never read)
    if (t3 > NT - 1) t3 = NT - 1;
    PH(0, 0, 0, af0, af1, 0, 0, 1, STAGE_A(1, 1, t1))
    PH(0, 0, 1, af1, af0, 0, 1, 0, STAGE_B(1, 1, t1))
    PH(0, 1, 0, af0, af1, 0, 1, 1, STAGE_A(0, 0, t2))
    PH(0, 1, 1, af1, af0, 1, 0, 0, STAGE_B(0, 0, t2))
    PH(1, 0, 0, af0, af1, 1, 0, 1, STAGE_A(0, 1, t2))
    PH(1, 0, 1, af1, af0, 1, 1, 0, STAGE_B(0, 1, t2))
    PH(1, 1, 0, af0, af1, 1, 1, 1, STAGE_A(1, 0, t3))
    PH(1, 1, 1, af1, af0, 0, 0, 0, STAGE_B(1, 0, t3))
  }
  asm volatile("s_waitcnt vmcnt(0)" ::: "memory");

#undef PH
#undef LDA
#undef LDB
#undef STAGE_A
#undef STAGE_B

  if (EPI == 0) {
#pragma unroll
    for (int m = 0; m < 8; ++m)
#pragma unroll
      for (int n = 0; n < 4; ++n)
#pragma unroll
        for (int r = 0; r < 4; ++r) {
          int row = m0 + wmB + m * 16 + quad * 4 + r;
          int col = n0 + wnB + n * 16 + l15;
          Cf[(size_t)row * N + col] = acc[m][n][r];
        }
  } else {
    const int colW = n0 + wnB;
    const int sel = colW >> 11;
    const int h = (colW >> 7) & 15;
    if (sel < 2) {
      ushort* dst = (sel == 0) ? C0 : C1;
#pragma unroll
      for (int m = 0; m < 8; ++m) {
        int rowb = m0 + wmB + m * 16 + quad * 4;
        int b = rowb >> 11, s = rowb & 2047;
#pragma unroll
        for (int n = 0; n < 4; ++n) {
          int d = (colW + n * 16 + l15) & 127;
#pragma unroll
          for (int r = 0; r < 4; ++r)
            dst[((size_t)(b * 16 + h) * 2048 + (s + r)) * 128 + d] =
                f2bf(acc[m][n][r]);
        }
      }
    } else {
#pragma unroll
      for (int m = 0; m < 8; ++m) {
        int rowb = m0 + wmB + m * 16 + quad * 4;
        int b = rowb >> 11, s = rowb & 2047;
#pragma unroll
        for (int n = 0; n < 4; ++n) {
          int d = (colW + n * 16 + l15) & 127;
          ushort4 pk;
          pk.x = f2bf(acc[m][n][0]);
          pk.y = f2bf(acc[m][n][1]);
          pk.z = f2bf(acc[m][n][2]);
          pk.w = f2bf(acc[m][n][3]);
          *(ushort4*)&C2[((size_t)(b * 16 + h) * 128 + d) * 2048 + s] = pk;
        }
      }
    }
  }
}

// ---------------------------------------------------------------- RoPE
// in-place on Q and K planes: [bh][s][128]. Q additionally pre-scaled by
// (1/sqrt(128))*log2(e) so attention can use exp2 with no per-tile scaling.
__global__ __launch_bounds__(256) void rope_kernel(
    ushort* __restrict__ Q, ushort* __restrict__ Kb,
    const float* __restrict__ cosT, const float* __restrict__ sinT) {
  unsigned gid = blockIdx.x * 256u + threadIdx.x;
  int d = gid & 63;
  int s = (gid >> 6) & 2047;
  int bh = (gid >> 17) & 63;
  const bool isK = (gid >> 23) != 0;
  ushort* buf = isK ? Kb : Q;
  const float sc = isK ? 1.0f
                       : 0.08838834764831845f * 1.4426950408889634f;
  size_t base = ((size_t)bh * 2048 + s) * 128;
  float x1 = bf2f(buf[base + d]);
  float x2 = bf2f(buf[base + d + 64]);
  float c = cosT[s * 64 + d];
  float sn = sinT[s * 64 + d];
  buf[base + d] = f2bf((x1 * c - x2 * sn) * sc);
  buf[base + d + 64] = f2bf((x1 * sn + x2 * c) * sc);
}

// ---------------------------------------------------------------- attention
// flash-style causal attention, transposed-score form, Q-tile = 256 rows.
// Grid: 512 blocks (8 q-groups x 64 bh), heavy-first: tq = 7-(bid>>6).
// 8 waves; each wave owns 32 q = 2 groups of 16 (rows +0 and +128).
// K/V staged once per 256 q-rows (2x fewer staged bytes), kf/av LDS reads
// SHARED between the two groups (2 MFMAs per read). 3-deep K/V ring ->
// 2-tile prefetch runway; exact vmcnt ledger (4/0), one barrier per tile.
// Softmax: defer-max (THR=8, log2 domain) + per-lane partial lsum (row-sum
// reduced once in epilogue, no per-tile sum shuffles).
// LDS: Ks 3x16K + Vs 3x16K + Ps 2x16K = 128 KiB -> 1 block/CU, 256 reg cap.
// Q [bh][s][128] (pre-scaled), K [bh][s][128], VT [bh][128][s],
// O -> [b][s][h*128+d] (bf16)
__global__ __launch_bounds__(512, 1) void attn_kernel(
    const ushort* __restrict__ Q, const ushort* __restrict__ Kb,
    const ushort* __restrict__ VT, ushort* __restrict__ O) {
  __shared__ __align__(16) ushort Ks[3][64 * 128];  // [k_local][d], xor(row&15)
  __shared__ __align__(16) ushort Vs[3][128 * 64];  // [d][s_local], xor(row&7)
  __shared__ __align__(16) ushort Ps[2][128 * 64];  // [q_local][k] per group
  const int t = threadIdx.x, lane = t & 63, w = t >> 6;  // w 0..7
  const int l15 = lane & 15, quad = lane >> 4;
  const int bid = blockIdx.x;
  const int tq = 7 - (bid >> 6);    // heavy-first, 256-row q-tiles
  const int bh = bid & 63;
  const int qrowA = tq * 256 + w * 16 + l15;  // group a row
  const int qrowB = qrowA + 128;              // group b row
  const size_t hbase = (size_t)bh * 2048 * 128;
  const float NEGINF = -__builtin_inff();

  // staging source bases (per-lane, tile-invariant). Per wave: 2 K + 2 V gld16.
  const int kr0 = w * 8 + quad, kr1 = w * 8 + 4 + quad;
  const ushort* kS0 = Kb + hbase + (size_t)kr0 * 128 + (l15 ^ (kr0 & 15)) * 8;
  const ushort* kS1 = Kb + hbase + (size_t)kr1 * 128 + (l15 ^ (kr1 & 15)) * 8;
  const int vr0 = w * 16 + (lane >> 3), vr1 = w * 16 + 8 + (lane >> 3);
  const ushort* vS0 = VT + hbase + (size_t)vr0 * 2048 + ((lane & 7) ^ (vr0 & 7)) * 8;
  const ushort* vS1 = VT + hbase + (size_t)vr1 * 2048 + ((lane & 7) ^ (vr1 & 7)) * 8;

  // Q fragments (B-operand): n=q=l15, k=d contiguous 8
  bf16x8 aqa[4], aqb[4];
#pragma unroll
  for (int kb = 0; kb < 4; kb++) {
    aqa[kb] = *(const bf16x8*)&Q[hbase + (size_t)qrowA * 128 + kb * 32 + quad * 8];
    aqb[kb] = *(const bf16x8*)&Q[hbase + (size_t)qrowB * 128 + kb * 32 + quad * 8];
  }

  float m2a = NEGINF, lsa = 0.f;  // lsa/lsb are PER-LANE partial row sums
  float m2b = NEGINF, lsb = 0.f;
  floatx4 oa[8], ob[8];  // O^T: row d = dj*16+quad*4+r, col q = l15
  const floatx4 zero = {0.f, 0.f, 0.f, 0.f};
#pragma unroll
  for (int dj = 0; dj < 8; dj++) { oa[dj] = zero; ob[dj] = zero; }

  const int ntk = 4 * tq + 4;  // 64-wide K-tiles (always >= 4)

#define STAGE(sl, tile)                                                 \
  { gld16(&Ks[sl][(w * 2 + 0) * 512], kS0 + (size_t)(tile) * 8192);     \
    gld16(&Ks[sl][(w * 2 + 1) * 512], kS1 + (size_t)(tile) * 8192);     \
    gld16(&Vs[sl][(w * 2 + 0) * 512], vS0 + (size_t)(tile) * 64);       \
    gld16(&Vs[sl][(w * 2 + 1) * 512], vS1 + (size_t)(tile) * 64); }

  // prologue: stage tiles 0,1 into slots 0,1; certify tile 0 (drain to 4)
  STAGE(0, 0)
  STAGE(1, 1)
  asm volatile("s_waitcnt vmcnt(4)" ::: "memory");
  __builtin_amdgcn_s_barrier();

  int sl = 0, s2 = 2;  // slot of tile tk / tile tk+2
  for (int tk = 0; tk < ntk; tk++) {
    const bool pf = (tk + 2 < ntk);
    if (pf) STAGE(s2, tk + 2)
    const ushort* Kc = &Ks[sl][0];
    const ushort* Vc = &Vs[sl][0];

    // ---- S^T = K.Q^T for both groups, kf shared
    floatx4 sa[4], sb[4];
#pragma unroll
    for (int j = 0; j < 4; j++) { sa[j] = zero; sb[j] = zero; }
#pragma unroll
    for (int kb = 0; kb < 4; kb++) {
#pragma unroll
      for (int j = 0; j < 4; j++) {
        int row = j * 16 + l15;
        int c = (kb * 4 + quad) ^ (row & 15);
        bf16x8 kf = *(const bf16x8*)&Kc[row * 128 + c * 8];
        sa[j] = __builtin_amdgcn_mfma_f32_16x16x32_bf16(kf, aqa[kb], sa[j], 0, 0, 0);
        sb[j] = __builtin_amdgcn_mfma_f32_16x16x32_bf16(kf, aqb[kb], sb[j], 0, 0, 0);
      }
    }

    // ---- causal mask (log2-domain scores). Group a needs it from tile 4tq,
    // group b from tile 4tq+2 (conservative, uniform conditions).
    if (tk >= 4 * tq) {
#pragma unroll
      for (int j = 0; j < 4; j++)
#pragma unroll
        for (int r = 0; r < 4; r++) {
          int kcol = tk * 64 + j * 16 + quad * 4 + r;
          if (kcol > qrowA) sa[j][r] = NEGINF;
        }
    }
    if (tk >= 4 * tq + 2) {
#pragma unroll
      for (int j = 0; j < 4; j++)
#pragma unroll
        for (int r = 0; r < 4; r++) {
          int kcol = tk * 64 + j * 16 + quad * 4 + r;
          if (kcol > qrowB) sb[j][r] = NEGINF;
        }
    }

    // ---- online softmax, defer-max THR=8, partial lsum (no sum shuffles).
    // Two independent chains -> ILP hides shfl/exp2 latency.
    {
      float mxa = sa[0][0], mxb = sb[0][0];
#pragma unroll
      for (int j = 0; j < 4; j++)
#pragma unroll
        for (int r = 0; r < 4; r++) {
          mxa = fmaxf(mxa, sa[j][r]);
          mxb = fmaxf(mxb, sb[j][r]);
        }
      mxa = fmaxf(mxa, __shfl_xor(mxa, 16));
      mxb = fmaxf(mxb, __shfl_xor(mxb, 16));
      mxa = fmaxf(mxa, __shfl_xor(mxa, 32));
      mxb = fmaxf(mxb, __shfl_xor(mxb, 32));
      if (__any(mxa > m2a + 8.0f)) {
        float mn = fmaxf(m2a, mxa);
        float al = __builtin_exp2f(m2a - mn);
        m2a = mn;
        lsa *= al;
#pragma unroll
        for (int dj = 0; dj < 8; dj++) oa[dj] *= al;
      }
      if (__any(mxb > m2b + 8.0f)) {
        float mn = fmaxf(m2b, mxb);
        float al = __builtin_exp2f(m2b - mn);
        m2b = mn;
        lsb *= al;
#pragma unroll
        for (int dj = 0; dj < 8; dj++) ob[dj] *= al;
      }
      float rsa = 0.f, rsb = 0.f;
#pragma unroll
      for (int j = 0; j < 4; j++)
#pragma unroll
        for (int r = 0; r < 4; r++) {
          float pa = __builtin_exp2f(sa[j][r] - m2a);
          float pb = __builtin_exp2f(sb[j][r] - m2b);
          sa[j][r] = pa; sb[j][r] = pb;
          rsa += pa; rsb += pb;
        }
      lsa += rsa;
      lsb += rsb;
    }

    // ---- P^T -> LDS (group a -> Ps[0], b -> Ps[1]); 8-el grp xor(l15&7)
#pragma unroll
    for (int j = 0; j < 4; j++) {
      int g = j * 2 + (quad >> 1);
      int gp = g ^ (l15 & 7);
      int off = (w * 16 + l15) * 64 + gp * 8 + (quad & 1) * 4;
      uint2 pva, pvb;
      pva.x = pk2bf(sa[j][0], sa[j][1]);
      pva.y = pk2bf(sa[j][2], sa[j][3]);
      pvb.x = pk2bf(sb[j][0], sb[j][1]);
      pvb.y = pk2bf(sb[j][2], sb[j][3]);
      *(uint2*)&Ps[0][off] = pva;
      *(uint2*)&Ps[1][off] = pvb;
    }

    // ---- O^T += V^T . P^T  (same-wave Ps write->read; av shared a/b)
    bf16x8 bpa[2], bpb[2];
#pragma unroll
    for (int kk = 0; kk < 2; kk++) {
      int g = kk * 4 + quad;
      int gp = g ^ (l15 & 7);
      bpa[kk] = *(const bf16x8*)&Ps[0][(w * 16 + l15) * 64 + gp * 8];
      bpb[kk] = *(const bf16x8*)&Ps[1][(w * 16 + l15) * 64 + gp * 8];
    }
#pragma unroll
    for (int kk = 0; kk < 2; kk++)
#pragma unroll
      for (int dj = 0; dj < 8; dj++) {
        int rowd = dj * 16 + l15;
        int c = (kk * 4 + quad) ^ (rowd & 7);
        bf16x8 av = *(const bf16x8*)&Vc[rowd * 64 + c * 8];
        oa[dj] = __builtin_amdgcn_mfma_f32_16x16x32_bf16(av, bpa[kk], oa[dj], 0, 0, 0);
        ob[dj] = __builtin_amdgcn_mfma_f32_16x16x32_bf16(av, bpb[kk], ob[dj], 0, 0, 0);
      }

    // ---- certify next tile (staged 1-2 iterations ago; ledger exact)
    if (pf) {
      asm volatile("s_waitcnt vmcnt(4)" ::: "memory");
    } else {
      asm volatile("s_waitcnt vmcnt(0)" ::: "memory");
    }
    __builtin_amdgcn_s_barrier();
    sl = (sl == 2) ? 0 : sl + 1;
    s2 = (s2 == 2) ? 0 : s2 + 1;
  }
#undef STAGE

  // epilogue: reduce partial row sums across the quad lanes, store both groups
  const int b = bh >> 4, h = bh & 15;
  lsa += __shfl_xor(lsa, 16);
  lsb += __shfl_xor(lsb, 16);
  lsa += __shfl_xor(lsa, 32);
  lsb += __shfl_xor(lsb, 32);
  const float rla = 1.0f / lsa;
  const float rlb = 1.0f / lsb;
  const size_t obaseA = ((size_t)(b * 2048 + qrowA)) * 2048 + h * 128;
  const size_t obaseB = ((size_t)(b * 2048 + qrowB)) * 2048 + h * 128;
#pragma unroll
  for (int dj = 0; dj < 8; dj++) {
    ushort4 pka, pkb;
    pka.x = f2bf(oa[dj][0] * rla);
    pka.y = f2bf(oa[dj][1] * rla);
    pka.z = f2bf(oa[dj][2] * rla);
    pka.w = f2bf(oa[dj][3] * rla);
    pkb.x = f2bf(ob[dj][0] * rlb);
    pkb.y = f2bf(ob[dj][1] * rlb);
    pkb.z = f2bf(ob[dj][2] * rlb);
    pkb.w = f2bf(ob[dj][3] * rlb);
    *(ushort4*)&O[obaseA + dj * 16 + quad * 4] = pka;
    *(ushort4*)&O[obaseB + dj * 16 + quad * 4] = pkb;
  }
}

// ---------------------------------------------------------------- launch
// All inputs/outputs fp32 (per reference). bf16 scratch:
//   d_out[0 .. 33.5MB)  : xbf (bf16 x), dead before GEMM2 overwrites d_out
//   ws[0, 33.5M)        : wqkvT (GEMM1 only) then Ob (attn -> GEMM2)
//   ws[33.5M, 42.0M)    : woutT
//   ws[42.0M, 75.5M)    : Q   [64][2048][128]
//   ws[75.5M, 109.1M)   : K   [64][2048][128]
//   ws[109.1M, 142.6M)  : VT  [64][128][2048]
extern "C" void kernel_launch(void* const* d_in, const int* in_sizes, int n_in,
                              void* d_out, int out_size, void* d_ws, size_t ws_size,
                              hipStream_t stream) {
  const float* x    = (const float*)d_in[0];
  const float* cosT = (const float*)d_in[1];
  const float* sinT = (const float*)d_in[2];
  const float* wqkv = (const float*)d_in[3];
  const float* wout = (const float*)d_in[4];
  float* out = (float*)d_out;
  char* ws = (char*)d_ws;

  ushort* xbf   = (ushort*)d_out;                      // 8192x2048 bf16 scratch
  ushort* wqkvT = (ushort*)(ws);                       // 6144x2048
  ushort* Ob    = (ushort*)(ws);                       // 8192x2048 (after GEMM1)
  ushort* woutT = (ushort*)(ws + 33554432);            // 2048x2048
  ushort* Qb    = (ushort*)(ws + 41943040);
  ushort* Kbuf  = (ushort*)(ws + 75497472);
  ushort* VTb   = (ushort*)(ws + 109051904);

  cvt_f32_bf16<<<16384, 256, 0, stream>>>(x, xbf);
  transpose_cvt<<<dim3(96, 32), 256, 0, stream>>>(wqkv, wqkvT, 2048, 6144);
  transpose_cvt<<<dim3(32, 32), 256, 0, stream>>>(wout, woutT, 2048, 2048);
  gemm256<1><<<dim3(24, 32), 512, 0, stream>>>(xbf, wqkvT, nullptr,
                                               Qb, Kbuf, VTb, 8192, 6144, 2048);
  rope_kernel<<<65536, 256, 0, stream>>>(Qb, Kbuf, cosT, sinT);
  attn_kernel<<<512, 512, 0, stream>>>(Qb, Kbuf, VTb, Ob);
  gemm256<0><<<dim3(8, 32), 512, 0, stream>>>(Ob, woutT, out,
                                              nullptr, nullptr, nullptr,
                                              8192, 2048, 2048);
}